// Round 9
// baseline (359.685 us; speedup 1.0000x reference)
//
#include <hip/hip_runtime.h>
#include <hip/hip_bf16.h>
#include <stdint.h>

typedef __bf16 bf16_t;
typedef __attribute__((ext_vector_type(8))) __bf16 bf16x8;
typedef __attribute__((ext_vector_type(4))) float f32x4;
typedef __attribute__((ext_vector_type(8))) unsigned short u16x8;

#define S_LEN 2048
#define DIM   4096
#define QKVN  6144
#define NHEAD 32
#define HDIM  128

typedef __attribute__((address_space(1))) unsigned int as1_u32;
typedef __attribute__((address_space(3))) unsigned int as3_u32;

__device__ __forceinline__ unsigned short f2bf(float f) {
  unsigned u = __builtin_bit_cast(unsigned, f);
  u += 0x7fffu + ((u >> 16) & 1u);
  return (unsigned short)(u >> 16);
}

__device__ __forceinline__ void gload_lds16(const void* g, void* l) {
  __builtin_amdgcn_global_load_lds(
      (as1_u32*)(unsigned long long)(uintptr_t)g,
      (as3_u32*)(unsigned int)(uintptr_t)l,
      16, 0, 0);
}

// Fused f32->bf16 conversion for all 5 inputs (one launch, grid-stride).
__global__ __launch_bounds__(256) void cvt5_kernel(const float* __restrict__ x,
                                                   const float* __restrict__ wq,
                                                   const float* __restrict__ wk,
                                                   const float* __restrict__ wv,
                                                   const float* __restrict__ wo,
                                                   ushort4* __restrict__ xb,
                                                   ushort4* __restrict__ wqkvb,
                                                   ushort4* __restrict__ wob) {
  const long N0 = 2097152;           // x  : 2048*4096/4
  const long N1 = N0 + 4194304;      // wq : 4096*4096/4
  const long N2 = N1 + 1048576;      // wk
  const long N3 = N2 + 1048576;      // wv
  const long N4 = N3 + 4194304;      // wo
  long idx = (long)blockIdx.x * 256 + threadIdx.x;
  long stride = (long)gridDim.x * 256;
  for (long i = idx; i < N4; i += stride) {
    const float4* s; ushort4* d; long o;
    if (i < N0)      { s = (const float4*)x;  d = xb;              o = i; }
    else if (i < N1) { s = (const float4*)wq; d = wqkvb;           o = i - N0; }
    else if (i < N2) { s = (const float4*)wk; d = wqkvb + 4194304; o = i - N1; }
    else if (i < N3) { s = (const float4*)wv; d = wqkvb + 5242880; o = i - N2; }
    else             { s = (const float4*)wo; d = wob;             o = i - N3; }
    float4 v = s[o];
    ushort4 r;
    r.x = f2bf(v.x); r.y = f2bf(v.y); r.z = f2bf(v.z); r.w = f2bf(v.w);
    d[o] = r;
  }
}

// ---- 256x256 8-phase GEMM (m201 geometry), BK=64, 8 waves (2M x 4N) -----
// C(M,N) = A(M,K) * B(N,K)^T. LDS 128KB: 2 dbuf x {A[2 half][128][64],
// B[2 half][128][64]} bf16. Per K-tile 4 phases, each:
//   {ds_read subtile | stage 1 half-tile} barrier; lgkm(0); setprio(1);
//   16 MFMA; setprio(0); [P3: vmcnt(4)] barrier;
// Ledger (hand-verified): reads P0=A0-3,B0-1  P1=B2-3  P2=A4-7  P3=none.
// Stages at tile t: P0->A.h0(t+1)[dbuf d^1], P1->A.h1(t+1)[d^1],
// P2->B.h0(t+2)[d], P3->B.h1(t+2)[d]. Each region consumed-before-staged
// (B fully read by P1-barrier, A by P2-barrier). vmcnt(4) at P3 leaves only
// the 2 B-halves of t+2 in flight => everything needed at t+1/P0 resident.
// Swizzle: chunk ^= (row&7) on both stage-source and read (conflict-free).
__device__ __forceinline__ bf16x8 fld(const char* half, int row, int chunk) {
  return *(const bf16x8*)(half + row * 128 + ((chunk ^ (row & 7)) << 4));
}

__device__ __forceinline__ void mfma8(const bf16x8 (*af)[2], const bf16x8 (*bf_)[2],
                                      f32x4 (*acc)[4], int mbase, int nbase) {
#pragma unroll
  for (int m = 0; m < 4; ++m)
#pragma unroll
    for (int n = 0; n < 2; ++n) {
      acc[mbase + m][nbase + n] = __builtin_amdgcn_mfma_f32_16x16x32_bf16(
          af[mbase + m][0], bf_[nbase + n][0], acc[mbase + m][nbase + n], 0, 0, 0);
      acc[mbase + m][nbase + n] = __builtin_amdgcn_mfma_f32_16x16x32_bf16(
          af[mbase + m][1], bf_[nbase + n][1], acc[mbase + m][nbase + n], 0, 0, 0);
    }
}

template <int OUTF32>
__global__ __launch_bounds__(512, 2) void gemm8p(const bf16_t* __restrict__ A,
                                                 const bf16_t* __restrict__ B,
                                                 void* __restrict__ Cout,
                                                 int M, int N, int K, int nxt) {
  __shared__ char lds[131072];
  const int tid = threadIdx.x;
  const int lane = tid & 63, w = tid >> 6;
  const int wm = w >> 2, wn = w & 3;       // 2 M-waves x 4 N-waves, 128x64 each
  const int lg = lane >> 4, lr = lane & 15;
  const int nwg = gridDim.x;
  const int orig = blockIdx.x;
  const int wgid = (orig & 7) * (nwg >> 3) + (orig >> 3);  // nwg % 8 == 0
  const int bx = wgid % nxt, by = wgid / nxt;
  const long rowA = (long)by * 256;
  const long rowB = (long)bx * 256;

  f32x4 acc[8][4];
  const f32x4 z4 = {0.f, 0.f, 0.f, 0.f};
#pragma unroll
  for (int i = 0; i < 8; ++i)
#pragma unroll
    for (int j = 0; j < 4; ++j) acc[i][j] = z4;

  // staging: half-tile = 128 rows x 8 chunks(16B) = 1024 chunks; this thread
  // handles chunks tid (row r0) and tid+512 (row r0+64); same xor key.
  const int r0 = tid >> 3, sl = tid & 7;
  const long xo  = (long)((sl ^ (r0 & 7)) << 3);
  const long aof = (rowA + r0) * (long)K + xo;   // A half0 chunk j0
  const long bof = (rowB + r0) * (long)K + xo;   // B half0 chunk j0
  const long j1  = (long)64 * K;                 // +64 rows (chunk j1)
  const long h1  = (long)128 * K;                // +128 rows (half 1)
  const int ld0 = tid * 16, ld1 = (tid + 512) * 16;

#define STG_A(K0, HALF, DBUF)                                                  \
  { char* hp = lds + (DBUF) * 65536 + (HALF) * 16384;                          \
    gload_lds16(A + aof + (HALF) * h1 + (K0),      hp + ld0);                  \
    gload_lds16(A + aof + (HALF) * h1 + j1 + (K0), hp + ld1); }
#define STG_B(K0, HALF, DBUF)                                                  \
  { char* hp = lds + (DBUF) * 65536 + 32768 + (HALF) * 16384;                  \
    gload_lds16(B + bof + (HALF) * h1 + (K0),      hp + ld0);                  \
    gload_lds16(B + bof + (HALF) * h1 + j1 + (K0), hp + ld1); }

  const int nt = K >> 6;   // K-tiles of 64
  const int bro = (wn & 1) * 64;

  // prologue: tile0 full + B halves of tile1 (12 loads); tile0 landed.
  STG_A(0, 0, 0); STG_A(0, 1, 0); STG_B(0, 0, 0); STG_B(0, 1, 0);
  STG_B(64, 0, 1); STG_B(64, 1, 1);
  asm volatile("s_waitcnt vmcnt(4)" ::: "memory");
  __builtin_amdgcn_s_barrier();

  bf16x8 af[8][2], bf_[4][2];

  for (int t = 0; t < nt; ++t) {
    const int d = t & 1;
    const char* Ah = lds + d * 65536 + wm * 16384;
    const char* Bh = lds + d * 65536 + 32768 + (wn >> 1) * 16384;
    const int k1 = (t + 1) << 6, k2 = (t + 2) << 6;
    // ---------------- P0: read A0-3,B0-1; stage A.h0(t+1) ----------------
#pragma unroll
    for (int m = 0; m < 4; ++m) {
      af[m][0] = fld(Ah, m * 16 + lr, lg);
      af[m][1] = fld(Ah, m * 16 + lr, 4 + lg);
    }
#pragma unroll
    for (int n = 0; n < 2; ++n) {
      bf_[n][0] = fld(Bh, bro + n * 16 + lr, lg);
      bf_[n][1] = fld(Bh, bro + n * 16 + lr, 4 + lg);
    }
    if (t + 1 < nt) STG_A(k1, 0, d ^ 1);
    __builtin_amdgcn_s_barrier();
    asm volatile("s_waitcnt lgkmcnt(0)" ::: "memory");
    __builtin_amdgcn_sched_barrier(0);
    __builtin_amdgcn_s_setprio(1);
    mfma8(af, bf_, acc, 0, 0);
    __builtin_amdgcn_s_setprio(0);
    __builtin_amdgcn_s_barrier();
    // ---------------- P1: read B2-3; stage A.h1(t+1) ----------------------
#pragma unroll
    for (int n = 2; n < 4; ++n) {
      bf_[n][0] = fld(Bh, bro + n * 16 + lr, lg);
      bf_[n][1] = fld(Bh, bro + n * 16 + lr, 4 + lg);
    }
    if (t + 1 < nt) STG_A(k1, 1, d ^ 1);
    __builtin_amdgcn_s_barrier();
    asm volatile("s_waitcnt lgkmcnt(0)" ::: "memory");
    __builtin_amdgcn_sched_barrier(0);
    __builtin_amdgcn_s_setprio(1);
    mfma8(af, bf_, acc, 0, 2);
    __builtin_amdgcn_s_setprio(0);
    __builtin_amdgcn_s_barrier();
    // ---------------- P2: read A4-7; stage B.h0(t+2) ----------------------
#pragma unroll
    for (int m = 4; m < 8; ++m) {
      af[m][0] = fld(Ah, m * 16 + lr, lg);
      af[m][1] = fld(Ah, m * 16 + lr, 4 + lg);
    }
    if (t + 2 < nt) STG_B(k2, 0, d);
    __builtin_amdgcn_s_barrier();
    asm volatile("s_waitcnt lgkmcnt(0)" ::: "memory");
    __builtin_amdgcn_sched_barrier(0);
    __builtin_amdgcn_s_setprio(1);
    mfma8(af, bf_, acc, 4, 0);
    __builtin_amdgcn_s_setprio(0);
    __builtin_amdgcn_s_barrier();
    // ---------------- P3: stage B.h1(t+2); vmcnt(4) ------------------------
    if (t + 2 < nt) STG_B(k2, 1, d);
    __builtin_amdgcn_s_barrier();
    __builtin_amdgcn_s_setprio(1);
    mfma8(af, bf_, acc, 4, 2);
    __builtin_amdgcn_s_setprio(0);
    if (t + 2 < nt) {
      asm volatile("s_waitcnt vmcnt(4)" ::: "memory");
    } else {
      asm volatile("s_waitcnt vmcnt(0)" ::: "memory");
    }
    __builtin_amdgcn_s_barrier();
  }
#undef STG_A
#undef STG_B

  const long crow = rowA + wm * 128;
  const long ccol = rowB + wn * 64;
  if (OUTF32) {
    float* C = (float*)Cout;
#pragma unroll
    for (int mf = 0; mf < 8; ++mf)
#pragma unroll
      for (int j = 0; j < 4; ++j) {
        long row = crow + mf * 16 + lg * 4 + j;
        float* cp = C + row * N + ccol + lr;
#pragma unroll
        for (int nf = 0; nf < 4; ++nf) cp[nf * 16] = acc[mf][nf][j];
      }
  } else {
    unsigned short* C = (unsigned short*)Cout;
#pragma unroll
    for (int mf = 0; mf < 8; ++mf)
#pragma unroll
      for (int j = 0; j < 4; ++j) {
        long row = crow + mf * 16 + lg * 4 + j;
        unsigned short* cp = C + row * N + ccol + lr;
#pragma unroll
        for (int nf = 0; nf < 4; ++nf) cp[nf * 16] = f2bf(acc[mf][nf][j]);
      }
  }
}

// In-place RoPE on bf16 qkv buffer (q heads 0..31, k heads 32..39).
__global__ __launch_bounds__(256) void rope_kernel(unsigned int* __restrict__ qkv32,
                                                   const float* __restrict__ cosb,
                                                   const float* __restrict__ sinb) {
  int t = blockIdx.x * 256 + threadIdx.x;
  int i  = t & 63;
  int sh = t >> 6;
  int hh = sh % 40;
  int s  = sh / 40;
  int col2 = (hh < 32) ? (hh * 64 + i) : (2048 + (hh - 32) * 64 + i);
  unsigned int* p = qkv32 + (long)s * (QKVN / 2) + col2;
  unsigned int v = *p;
  float tr = __builtin_bit_cast(float, (v & 0xffffu) << 16);
  float ti = __builtin_bit_cast(float, v & 0xffff0000u);
  float c  = cosb[s * 64 + i];
  float sn = sinb[s * 64 + i];
  float orr = tr * c - ti * sn;
  float oi  = tr * sn + ti * c;
  *p = (unsigned int)f2bf(orr) | ((unsigned int)f2bf(oi) << 16);
}

// V transpose: vT[kh][hd][s] from qkv[s][5120 + kh*128 + hd].
__global__ __launch_bounds__(256) void vtrans_kernel(const bf16_t* __restrict__ qkv,
                                                     bf16_t* __restrict__ vT) {
  const int kh = blockIdx.x;
  const int hd = threadIdx.x & 127;
  const int s0 = blockIdx.y * 16 + (threadIdx.x >> 7) * 8;
  u16x8 v;
#pragma unroll
  for (int e = 0; e < 8; ++e)
    v[e] = *(const unsigned short*)(qkv + (long)(s0 + e) * QKVN + 5120 + kh * HDIM + hd);
  *(u16x8*)(vT + ((long)kh * HDIM + hd) * S_LEN + s0) = v;
}

// Flash attention: block = (128 q-rows, 1 head), 8 waves x 16 q-rows, KVBLK=64.
__global__ __launch_bounds__(512) void attn_kernel(const bf16_t* __restrict__ qkv,
                                                   const bf16_t* __restrict__ vT,
                                                   unsigned short* __restrict__ ob) {
  __shared__ bf16_t Kt[64 * 128];     // 16 KB, swizzled
  __shared__ bf16_t Vt[128 * 64];     // 16 KB, swizzled (holds V^T)
  __shared__ bf16_t Pl[8 * 16 * 64];  // 16 KB, per-wave P, swizzled
  const int h  = blockIdx.x;
  const int qi = 15 - (int)blockIdx.y;   // heavy blocks dispatched first
  const int qb = qi * 128;
  const int kh = h >> 2;                 // REPEATS = 4
  const int tid = threadIdx.x, lane = tid & 63, w = tid >> 6;
  const int lg = lane >> 4, lr = lane & 15;
  const int qrow0 = qb + w * 16;

  bf16x8 qf[4];
  const bf16_t* qptr = qkv + (long)(qrow0 + lr) * QKVN + h * HDIM + lg * 8;
#pragma unroll
  for (int kk = 0; kk < 4; ++kk) qf[kk] = *(const bf16x8*)(qptr + kk * 32);

  const f32x4 z4 = {0.f, 0.f, 0.f, 0.f};
  f32x4 oacc[8];
#pragma unroll
  for (int c = 0; c < 8; ++c) oacc[c] = z4;
  float m[4]    = {-1e30f, -1e30f, -1e30f, -1e30f};
  float lsum[4] = {0.f, 0.f, 0.f, 0.f};

  char* KtB = (char*)Kt;
  char* VtB = (char*)Vt;
  char* PlB = (char*)Pl + w * 2048;
  const float scale = 0.08838834764831845f;
  const int ntiles = 2 * qi + 2;
  const int wqmax = qrow0 + 15;

  for (int t = 0; t < ntiles; ++t) {
    const int kv0 = t * 64;
    __syncthreads();
#pragma unroll
    for (int it = 0; it < 2; ++it) {
      int cch = tid + it * 512;
      int r = cch >> 4, c = cch & 15;
      const bf16_t* src = qkv + (long)(kv0 + r) * QKVN + 4096 + kh * HDIM
                          + ((c ^ (r & 7)) * 8);
      gload_lds16(src, KtB + cch * 16);
    }
#pragma unroll
    for (int it = 0; it < 2; ++it) {
      int cch = tid + it * 512;
      int hd = cch >> 3, c = cch & 7;
      const bf16_t* src = vT + ((long)kh * HDIM + hd) * S_LEN + kv0
                          + ((c ^ (hd & 7)) * 8);
      gload_lds16(src, VtB + cch * 16);
    }
    __syncthreads();
    if (kv0 > wqmax) continue;  // fully masked for this wave (barriers done)

    f32x4 sf[4];
#pragma unroll
    for (int f = 0; f < 4; ++f) {
      f32x4 a = z4;
      int n = f * 16 + lr;
      int rb = n * 256, sw = (n & 7) << 4;
#pragma unroll
      for (int kk = 0; kk < 4; ++kk) {
        bf16x8 kf = *(const bf16x8*)(KtB + rb + (((kk * 4 + lg) * 16) ^ sw));
        a = __builtin_amdgcn_mfma_f32_16x16x32_bf16(qf[kk], kf, a, 0, 0, 0);
      }
      sf[f] = a;
    }

    float sc_arr[4];
#pragma unroll
    for (int j = 0; j < 4; ++j) {
      int qrow = qrow0 + lg * 4 + j;
      float sv[4];
#pragma unroll
      for (int f = 0; f < 4; ++f) {
        float s = sf[f][j] * scale;
        if (kv0 + f * 16 + lr > qrow) s = -1e9f;
        sv[f] = s;
      }
      float mx = fmaxf(fmaxf(sv[0], sv[1]), fmaxf(sv[2], sv[3]));
      mx = fmaxf(mx, __shfl_xor(mx, 1));
      mx = fmaxf(mx, __shfl_xor(mx, 2));
      mx = fmaxf(mx, __shfl_xor(mx, 4));
      mx = fmaxf(mx, __shfl_xor(mx, 8));
      float mn = fmaxf(m[j], mx);
      float p[4];
#pragma unroll
      for (int f = 0; f < 4; ++f) p[f] = __expf(sv[f] - mn);
      float ps = (p[0] + p[1]) + (p[2] + p[3]);
      ps += __shfl_xor(ps, 1);
      ps += __shfl_xor(ps, 2);
      ps += __shfl_xor(ps, 4);
      ps += __shfl_xor(ps, 8);
      float sc = __expf(m[j] - mn);
      lsum[j] = lsum[j] * sc + ps;
      m[j] = mn;
      sc_arr[j] = sc;
      int row = lg * 4 + j;
      int swp = (row & 7) << 4;
#pragma unroll
      for (int f = 0; f < 4; ++f)
        *(unsigned short*)(PlB + row * 128 + (((f * 16 + lr) * 2) ^ swp)) = f2bf(p[f]);
    }
#pragma unroll
    for (int c = 0; c < 8; ++c)
#pragma unroll
      for (int j = 0; j < 4; ++j) oacc[c][j] *= sc_arr[j];

    bf16x8 pfr[2];
#pragma unroll
    for (int kk = 0; kk < 2; ++kk)
      pfr[kk] = *(const bf16x8*)(PlB + lr * 128 + (((kk * 4 + lg) * 16) ^ ((lr & 7) << 4)));
#pragma unroll
    for (int c = 0; c < 8; ++c) {
      int hd = c * 16 + lr;
      int rb = hd * 128, sw = (hd & 7) << 4;
#pragma unroll
      for (int kk = 0; kk < 2; ++kk) {
        bf16x8 vf = *(const bf16x8*)(VtB + rb + (((kk * 4 + lg) * 16) ^ sw));
        oacc[c] = __builtin_amdgcn_mfma_f32_16x16x32_bf16(pfr[kk], vf, oacc[c], 0, 0, 0);
      }
    }
  }

  float rl[4];
#pragma unroll
  for (int j = 0; j < 4; ++j) rl[j] = 1.f / lsum[j];
#pragma unroll
  for (int c = 0; c < 8; ++c)
#pragma unroll
    for (int j = 0; j < 4; ++j) {
      long row = qrow0 + lg * 4 + j;
      ob[row * 4096 + h * 128 + c * 16 + lr] = f2bf(oacc[c][j] * rl[j]);
    }
}

extern "C" void kernel_launch(void* const* d_in, const int* in_sizes, int n_in,
                              void* d_out, int out_size, void* d_ws, size_t ws_size,
                              hipStream_t stream) {
  const float* x  = (const float*)d_in[0];
  const float* wq = (const float*)d_in[1];
  const float* wk = (const float*)d_in[2];
  const float* wv = (const float*)d_in[3];
  const float* wo = (const float*)d_in[4];
  const float* fc = (const float*)d_in[5];
  const float* fs = (const float*)d_in[6];

  char* ws = (char*)d_ws;
  bf16_t* xb    = (bf16_t*)(ws + 0);          // 2048x4096 (dead after gemm1)
  bf16_t* wqkvb = (bf16_t*)(ws + 16777216);   // 6144x4096
  bf16_t* wob   = (bf16_t*)(ws + 67108864);   // 4096x4096
  bf16_t* qkv   = (bf16_t*)(ws + 100663296);  // 2048x6144
  bf16_t* ob    = (bf16_t*)(ws + 125829120);  // 2048x4096
  bf16_t* vT    = (bf16_t*)(ws + 0);          // 8x128x2048 (4 MB, reuses xb)

  cvt5_kernel<<<2048, 256, 0, stream>>>(x, wq, wk, wv, wo,
                                        (ushort4*)xb, (ushort4*)wqkvb, (ushort4*)wob);

  gemm8p<0><<<192, 512, 0, stream>>>(xb, wqkvb, qkv, 2048, 6144, 4096, 24);
  vtrans_kernel<<<dim3(8, 128), 256, 0, stream>>>(qkv, vT);
  rope_kernel<<<20480, 256, 0, stream>>>((unsigned int*)qkv, fc, fs);
  attn_kernel<<<dim3(32, 16), 512, 0, stream>>>(qkv, vT, (unsigned short*)ob);
  gemm8p<1><<<128, 512, 0, stream>>>(ob, wob, d_out, 2048, 4096, 4096, 16);
}

// Round 10
// 330.110 us; speedup vs baseline: 1.0896x; 1.0896x over previous
//
#include <hip/hip_runtime.h>
#include <hip/hip_bf16.h>
#include <stdint.h>

typedef __bf16 bf16_t;
typedef __attribute__((ext_vector_type(8))) __bf16 bf16x8;
typedef __attribute__((ext_vector_type(4))) float f32x4;
typedef __attribute__((ext_vector_type(8))) unsigned short u16x8;

#define S_LEN 2048
#define DIM   4096
#define QKVN  6144
#define NHEAD 32
#define HDIM  128

typedef __attribute__((address_space(1))) unsigned int as1_u32;
typedef __attribute__((address_space(3))) unsigned int as3_u32;

__device__ __forceinline__ unsigned short f2bf(float f) {
  unsigned u = __builtin_bit_cast(unsigned, f);
  u += 0x7fffu + ((u >> 16) & 1u);
  return (unsigned short)(u >> 16);
}

__device__ __forceinline__ void gload_lds16(const void* g, void* l) {
  __builtin_amdgcn_global_load_lds(
      (as1_u32*)(unsigned long long)(uintptr_t)g,
      (as3_u32*)(unsigned int)(uintptr_t)l,
      16, 0, 0);
}

// Fused f32->bf16 conversion for all 5 inputs (one launch, grid-stride).
__global__ __launch_bounds__(256) void cvt5_kernel(const float* __restrict__ x,
                                                   const float* __restrict__ wq,
                                                   const float* __restrict__ wk,
                                                   const float* __restrict__ wv,
                                                   const float* __restrict__ wo,
                                                   ushort4* __restrict__ xb,
                                                   ushort4* __restrict__ wqkvb,
                                                   ushort4* __restrict__ wob) {
  const long N0 = 2097152;           // x  : 2048*4096/4
  const long N1 = N0 + 4194304;      // wq : 4096*4096/4
  const long N2 = N1 + 1048576;      // wk
  const long N3 = N2 + 1048576;      // wv
  const long N4 = N3 + 4194304;      // wo
  long idx = (long)blockIdx.x * 256 + threadIdx.x;
  long stride = (long)gridDim.x * 256;
  for (long i = idx; i < N4; i += stride) {
    const float4* s; ushort4* d; long o;
    if (i < N0)      { s = (const float4*)x;  d = xb;              o = i; }
    else if (i < N1) { s = (const float4*)wq; d = wqkvb;           o = i - N0; }
    else if (i < N2) { s = (const float4*)wk; d = wqkvb + 4194304; o = i - N1; }
    else if (i < N3) { s = (const float4*)wv; d = wqkvb + 5242880; o = i - N2; }
    else             { s = (const float4*)wo; d = wob;             o = i - N3; }
    float4 v = s[o];
    ushort4 r;
    r.x = f2bf(v.x); r.y = f2bf(v.y); r.z = f2bf(v.z); r.w = f2bf(v.w);
    d[o] = r;
  }
}

// ---- 256x256 8-phase GEMM (m201 geometry), BK=64, 8 waves (2M x 4N) -----
// (R9-verified: QKV 115.9us, MfmaUtil 37%, conflicts 0.)
__device__ __forceinline__ bf16x8 fld(const char* half, int row, int chunk) {
  return *(const bf16x8*)(half + row * 128 + ((chunk ^ (row & 7)) << 4));
}

__device__ __forceinline__ void mfma8(const bf16x8 (*af)[2], const bf16x8 (*bf_)[2],
                                      f32x4 (*acc)[4], int mbase, int nbase) {
#pragma unroll
  for (int m = 0; m < 4; ++m)
#pragma unroll
    for (int n = 0; n < 2; ++n) {
      acc[mbase + m][nbase + n] = __builtin_amdgcn_mfma_f32_16x16x32_bf16(
          af[mbase + m][0], bf_[nbase + n][0], acc[mbase + m][nbase + n], 0, 0, 0);
      acc[mbase + m][nbase + n] = __builtin_amdgcn_mfma_f32_16x16x32_bf16(
          af[mbase + m][1], bf_[nbase + n][1], acc[mbase + m][nbase + n], 0, 0, 0);
    }
}

template <int OUTF32>
__global__ __launch_bounds__(512, 2) void gemm8p(const bf16_t* __restrict__ A,
                                                 const bf16_t* __restrict__ B,
                                                 void* __restrict__ Cout,
                                                 int M, int N, int K, int nxt) {
  __shared__ char lds[131072];
  const int tid = threadIdx.x;
  const int lane = tid & 63, w = tid >> 6;
  const int wm = w >> 2, wn = w & 3;       // 2 M-waves x 4 N-waves, 128x64 each
  const int lg = lane >> 4, lr = lane & 15;
  const int nwg = gridDim.x;
  const int orig = blockIdx.x;
  const int wgid = (orig & 7) * (nwg >> 3) + (orig >> 3);  // nwg % 8 == 0
  const int bx = wgid % nxt, by = wgid / nxt;
  const long rowA = (long)by * 256;
  const long rowB = (long)bx * 256;

  f32x4 acc[8][4];
  const f32x4 z4 = {0.f, 0.f, 0.f, 0.f};
#pragma unroll
  for (int i = 0; i < 8; ++i)
#pragma unroll
    for (int j = 0; j < 4; ++j) acc[i][j] = z4;

  const int r0 = tid >> 3, sl = tid & 7;
  const long xo  = (long)((sl ^ (r0 & 7)) << 3);
  const long aof = (rowA + r0) * (long)K + xo;
  const long bof = (rowB + r0) * (long)K + xo;
  const long j1  = (long)64 * K;
  const long h1  = (long)128 * K;
  const int ld0 = tid * 16, ld1 = (tid + 512) * 16;

#define STG_A(K0, HALF, DBUF)                                                  \
  { char* hp = lds + (DBUF) * 65536 + (HALF) * 16384;                          \
    gload_lds16(A + aof + (HALF) * h1 + (K0),      hp + ld0);                  \
    gload_lds16(A + aof + (HALF) * h1 + j1 + (K0), hp + ld1); }
#define STG_B(K0, HALF, DBUF)                                                  \
  { char* hp = lds + (DBUF) * 65536 + 32768 + (HALF) * 16384;                  \
    gload_lds16(B + bof + (HALF) * h1 + (K0),      hp + ld0);                  \
    gload_lds16(B + bof + (HALF) * h1 + j1 + (K0), hp + ld1); }

  const int nt = K >> 6;
  const int bro = (wn & 1) * 64;

  STG_A(0, 0, 0); STG_A(0, 1, 0); STG_B(0, 0, 0); STG_B(0, 1, 0);
  STG_B(64, 0, 1); STG_B(64, 1, 1);
  asm volatile("s_waitcnt vmcnt(4)" ::: "memory");
  __builtin_amdgcn_s_barrier();

  bf16x8 af[8][2], bf_[4][2];

  for (int t = 0; t < nt; ++t) {
    const int d = t & 1;
    const char* Ah = lds + d * 65536 + wm * 16384;
    const char* Bh = lds + d * 65536 + 32768 + (wn >> 1) * 16384;
    const int k1 = (t + 1) << 6, k2 = (t + 2) << 6;
#pragma unroll
    for (int m = 0; m < 4; ++m) {
      af[m][0] = fld(Ah, m * 16 + lr, lg);
      af[m][1] = fld(Ah, m * 16 + lr, 4 + lg);
    }
#pragma unroll
    for (int n = 0; n < 2; ++n) {
      bf_[n][0] = fld(Bh, bro + n * 16 + lr, lg);
      bf_[n][1] = fld(Bh, bro + n * 16 + lr, 4 + lg);
    }
    if (t + 1 < nt) STG_A(k1, 0, d ^ 1);
    __builtin_amdgcn_s_barrier();
    asm volatile("s_waitcnt lgkmcnt(0)" ::: "memory");
    __builtin_amdgcn_sched_barrier(0);
    __builtin_amdgcn_s_setprio(1);
    mfma8(af, bf_, acc, 0, 0);
    __builtin_amdgcn_s_setprio(0);
    __builtin_amdgcn_s_barrier();
#pragma unroll
    for (int n = 2; n < 4; ++n) {
      bf_[n][0] = fld(Bh, bro + n * 16 + lr, lg);
      bf_[n][1] = fld(Bh, bro + n * 16 + lr, 4 + lg);
    }
    if (t + 1 < nt) STG_A(k1, 1, d ^ 1);
    __builtin_amdgcn_s_barrier();
    asm volatile("s_waitcnt lgkmcnt(0)" ::: "memory");
    __builtin_amdgcn_sched_barrier(0);
    __builtin_amdgcn_s_setprio(1);
    mfma8(af, bf_, acc, 0, 2);
    __builtin_amdgcn_s_setprio(0);
    __builtin_amdgcn_s_barrier();
#pragma unroll
    for (int m = 4; m < 8; ++m) {
      af[m][0] = fld(Ah, m * 16 + lr, lg);
      af[m][1] = fld(Ah, m * 16 + lr, 4 + lg);
    }
    if (t + 2 < nt) STG_B(k2, 0, d);
    __builtin_amdgcn_s_barrier();
    asm volatile("s_waitcnt lgkmcnt(0)" ::: "memory");
    __builtin_amdgcn_sched_barrier(0);
    __builtin_amdgcn_s_setprio(1);
    mfma8(af, bf_, acc, 4, 0);
    __builtin_amdgcn_s_setprio(0);
    __builtin_amdgcn_s_barrier();
    if (t + 2 < nt) STG_B(k2, 1, d);
    __builtin_amdgcn_s_barrier();
    __builtin_amdgcn_s_setprio(1);
    mfma8(af, bf_, acc, 4, 2);
    __builtin_amdgcn_s_setprio(0);
    if (t + 2 < nt) {
      asm volatile("s_waitcnt vmcnt(4)" ::: "memory");
    } else {
      asm volatile("s_waitcnt vmcnt(0)" ::: "memory");
    }
    __builtin_amdgcn_s_barrier();
  }
#undef STG_A
#undef STG_B

  const long crow = rowA + wm * 128;
  const long ccol = rowB + wn * 64;
  if (OUTF32) {
    float* C = (float*)Cout;
#pragma unroll
    for (int mf = 0; mf < 8; ++mf)
#pragma unroll
      for (int j = 0; j < 4; ++j) {
        long row = crow + mf * 16 + lg * 4 + j;
        float* cp = C + row * N + ccol + lr;
#pragma unroll
        for (int nf = 0; nf < 4; ++nf) cp[nf * 16] = acc[mf][nf][j];
      }
  } else {
    unsigned short* C = (unsigned short*)Cout;
#pragma unroll
    for (int mf = 0; mf < 8; ++mf)
#pragma unroll
      for (int j = 0; j < 4; ++j) {
        long row = crow + mf * 16 + lg * 4 + j;
        unsigned short* cp = C + row * N + ccol + lr;
#pragma unroll
        for (int nf = 0; nf < 4; ++nf) cp[nf * 16] = f2bf(acc[mf][nf][j]);
      }
  }
}

// ---- 256x128 4-phase GEMM (rect variant of gemm8p), BK=64, 8 waves ------
// 4M x 2N waves, wave tile 64x64, acc[4][4]. LDS 96KB: 2 dbuf x (A 32KB +
// B 16KB). Phases: P0 rd{A01,B01}+stgA.h0(t+1,~d); P1 rd{B23}+stgA.h1; P2
// rd{A23}+stgB(t+2,d) [B(t) consumed by P1 barrier]; P3 MFMA+vmcnt(2)
// [only B(t+2) in flight => A(t+1),B(t+1) resident at t+1 entry].
template <int OUTF32>
__global__ __launch_bounds__(512, 2) void gemm8r(const bf16_t* __restrict__ A,
                                                 const bf16_t* __restrict__ B,
                                                 void* __restrict__ Cout,
                                                 int M, int N, int K, int nxt) {
  __shared__ char lds[98304];
  const int tid = threadIdx.x;
  const int lane = tid & 63, w = tid >> 6;
  const int wm = w >> 1, wn = w & 1;       // 4 M-waves x 2 N-waves
  const int lg = lane >> 4, lr = lane & 15;
  const int nwg = gridDim.x;
  const int orig = blockIdx.x;
  const int wgid = (orig & 7) * (nwg >> 3) + (orig >> 3);  // nwg % 8 == 0
  const int bx = wgid % nxt, by = wgid / nxt;
  const long rowA = (long)by * 256;
  const long rowB = (long)bx * 128;

  f32x4 acc[4][4];
  const f32x4 z4 = {0.f, 0.f, 0.f, 0.f};
#pragma unroll
  for (int i = 0; i < 4; ++i)
#pragma unroll
    for (int j = 0; j < 4; ++j) acc[i][j] = z4;

  const int r0 = tid >> 3, sl = tid & 7;
  const long xo  = (long)((sl ^ (r0 & 7)) << 3);
  const long aof = (rowA + r0) * (long)K + xo;
  const long bof = (rowB + r0) * (long)K + xo;
  const long r64 = (long)64 * K;
  const int ld0 = tid * 16, ld1 = (tid + 512) * 16;

  // A region: rows 0..255 x 128B (32KB). half H = rows H*128..H*128+127.
#define RSTG_A(K0, HALF, DBUF)                                                 \
  { char* ap = lds + (DBUF) * 49152 + (HALF) * 16384;                          \
    gload_lds16(A + aof + (HALF) * 2 * r64 + (K0),       ap + ld0);            \
    gload_lds16(A + aof + (HALF) * 2 * r64 + r64 + (K0), ap + ld1); }
  // B region: rows 0..127 x 128B (16KB) at +32768.
#define RSTG_B(K0, DBUF)                                                       \
  { char* bp = lds + (DBUF) * 49152 + 32768;                                   \
    gload_lds16(B + bof + (K0),       bp + ld0);                               \
    gload_lds16(B + bof + r64 + (K0), bp + ld1); }

  const int nt = K >> 6;

  // prologue: A(0) full + B(0) -> dbuf0; B(1) -> dbuf1; tile0 landed.
  RSTG_A(0, 0, 0); RSTG_A(0, 1, 0); RSTG_B(0, 0);
  RSTG_B(64, 1);
  asm volatile("s_waitcnt vmcnt(2)" ::: "memory");
  __builtin_amdgcn_s_barrier();

  bf16x8 af[4][2], bf_[4][2];

  for (int t = 0; t < nt; ++t) {
    const int d = t & 1;
    const char* Ar = lds + d * 49152;
    const char* Br = Ar + 32768;
    const int arow = wm * 64, brow = wn * 64;
    const int k1 = (t + 1) << 6, k2 = (t + 2) << 6;
    // ---- P0: read A0-1,B0-1; stage A.h0(t+1) ----
#pragma unroll
    for (int m = 0; m < 2; ++m) {
      af[m][0] = fld(Ar, arow + m * 16 + lr, lg);
      af[m][1] = fld(Ar, arow + m * 16 + lr, 4 + lg);
    }
#pragma unroll
    for (int n = 0; n < 2; ++n) {
      bf_[n][0] = fld(Br, brow + n * 16 + lr, lg);
      bf_[n][1] = fld(Br, brow + n * 16 + lr, 4 + lg);
    }
    if (t + 1 < nt) RSTG_A(k1, 0, d ^ 1);
    __builtin_amdgcn_s_barrier();
    asm volatile("s_waitcnt lgkmcnt(0)" ::: "memory");
    __builtin_amdgcn_sched_barrier(0);
    __builtin_amdgcn_s_setprio(1);
#pragma unroll
    for (int m = 0; m < 2; ++m)
#pragma unroll
      for (int n = 0; n < 2; ++n) {
        acc[m][n] = __builtin_amdgcn_mfma_f32_16x16x32_bf16(af[m][0], bf_[n][0], acc[m][n], 0, 0, 0);
        acc[m][n] = __builtin_amdgcn_mfma_f32_16x16x32_bf16(af[m][1], bf_[n][1], acc[m][n], 0, 0, 0);
      }
    __builtin_amdgcn_s_setprio(0);
    __builtin_amdgcn_s_barrier();
    // ---- P1: read B2-3; stage A.h1(t+1) ----
#pragma unroll
    for (int n = 2; n < 4; ++n) {
      bf_[n][0] = fld(Br, brow + n * 16 + lr, lg);
      bf_[n][1] = fld(Br, brow + n * 16 + lr, 4 + lg);
    }
    if (t + 1 < nt) RSTG_A(k1, 1, d ^ 1);
    __builtin_amdgcn_s_barrier();
    asm volatile("s_waitcnt lgkmcnt(0)" ::: "memory");
    __builtin_amdgcn_sched_barrier(0);
    __builtin_amdgcn_s_setprio(1);
#pragma unroll
    for (int m = 0; m < 2; ++m)
#pragma unroll
      for (int n = 2; n < 4; ++n) {
        acc[m][n] = __builtin_amdgcn_mfma_f32_16x16x32_bf16(af[m][0], bf_[n][0], acc[m][n], 0, 0, 0);
        acc[m][n] = __builtin_amdgcn_mfma_f32_16x16x32_bf16(af[m][1], bf_[n][1], acc[m][n], 0, 0, 0);
      }
    __builtin_amdgcn_s_setprio(0);
    __builtin_amdgcn_s_barrier();
    // ---- P2: read A2-3; stage B(t+2) ----
#pragma unroll
    for (int m = 2; m < 4; ++m) {
      af[m][0] = fld(Ar, arow + m * 16 + lr, lg);
      af[m][1] = fld(Ar, arow + m * 16 + lr, 4 + lg);
    }
    if (t + 2 < nt) RSTG_B(k2, d);
    __builtin_amdgcn_s_barrier();
    asm volatile("s_waitcnt lgkmcnt(0)" ::: "memory");
    __builtin_amdgcn_sched_barrier(0);
    __builtin_amdgcn_s_setprio(1);
#pragma unroll
    for (int m = 2; m < 4; ++m)
#pragma unroll
      for (int n = 0; n < 2; ++n) {
        acc[m][n] = __builtin_amdgcn_mfma_f32_16x16x32_bf16(af[m][0], bf_[n][0], acc[m][n], 0, 0, 0);
        acc[m][n] = __builtin_amdgcn_mfma_f32_16x16x32_bf16(af[m][1], bf_[n][1], acc[m][n], 0, 0, 0);
      }
    __builtin_amdgcn_s_setprio(0);
    __builtin_amdgcn_s_barrier();
    // ---- P3: MFMA only; vmcnt(2) ----
    __builtin_amdgcn_s_setprio(1);
#pragma unroll
    for (int m = 2; m < 4; ++m)
#pragma unroll
      for (int n = 2; n < 4; ++n) {
        acc[m][n] = __builtin_amdgcn_mfma_f32_16x16x32_bf16(af[m][0], bf_[n][0], acc[m][n], 0, 0, 0);
        acc[m][n] = __builtin_amdgcn_mfma_f32_16x16x32_bf16(af[m][1], bf_[n][1], acc[m][n], 0, 0, 0);
      }
    __builtin_amdgcn_s_setprio(0);
    if (t + 2 < nt) {
      asm volatile("s_waitcnt vmcnt(2)" ::: "memory");
    } else {
      asm volatile("s_waitcnt vmcnt(0)" ::: "memory");
    }
    __builtin_amdgcn_s_barrier();
  }
#undef RSTG_A
#undef RSTG_B

  const long crow = rowA + wm * 64;
  const long ccol = rowB + wn * 64;
  if (OUTF32) {
    float* C = (float*)Cout;
#pragma unroll
    for (int mf = 0; mf < 4; ++mf)
#pragma unroll
      for (int j = 0; j < 4; ++j) {
        long row = crow + mf * 16 + lg * 4 + j;
        float* cp = C + row * N + ccol + lr;
#pragma unroll
        for (int nf = 0; nf < 4; ++nf) cp[nf * 16] = acc[mf][nf][j];
      }
  } else {
    unsigned short* C = (unsigned short*)Cout;
#pragma unroll
    for (int mf = 0; mf < 4; ++mf)
#pragma unroll
      for (int j = 0; j < 4; ++j) {
        long row = crow + mf * 16 + lg * 4 + j;
        unsigned short* cp = C + row * N + ccol + lr;
#pragma unroll
        for (int nf = 0; nf < 4; ++nf) cp[nf * 16] = f2bf(acc[mf][nf][j]);
      }
  }
}

// In-place RoPE on bf16 qkv buffer (q heads 0..31, k heads 32..39).
__global__ __launch_bounds__(256) void rope_kernel(unsigned int* __restrict__ qkv32,
                                                   const float* __restrict__ cosb,
                                                   const float* __restrict__ sinb) {
  int t = blockIdx.x * 256 + threadIdx.x;
  int i  = t & 63;
  int sh = t >> 6;
  int hh = sh % 40;
  int s  = sh / 40;
  int col2 = (hh < 32) ? (hh * 64 + i) : (2048 + (hh - 32) * 64 + i);
  unsigned int* p = qkv32 + (long)s * (QKVN / 2) + col2;
  unsigned int v = *p;
  float tr = __builtin_bit_cast(float, (v & 0xffffu) << 16);
  float ti = __builtin_bit_cast(float, v & 0xffff0000u);
  float c  = cosb[s * 64 + i];
  float sn = sinb[s * 64 + i];
  float orr = tr * c - ti * sn;
  float oi  = tr * sn + ti * c;
  *p = (unsigned int)f2bf(orr) | ((unsigned int)f2bf(oi) << 16);
}

// V transpose: vT[kh][hd][s] from qkv[s][5120 + kh*128 + hd].
__global__ __launch_bounds__(256) void vtrans_kernel(const bf16_t* __restrict__ qkv,
                                                     bf16_t* __restrict__ vT) {
  const int kh = blockIdx.x;
  const int hd = threadIdx.x & 127;
  const int s0 = blockIdx.y * 16 + (threadIdx.x >> 7) * 8;
  u16x8 v;
#pragma unroll
  for (int e = 0; e < 8; ++e)
    v[e] = *(const unsigned short*)(qkv + (long)(s0 + e) * QKVN + 5120 + kh * HDIM + hd);
  *(u16x8*)(vT + ((long)kh * HDIM + hd) * S_LEN + s0) = v;
}

// Flash attention: block = (128 q-rows, 1 head), 8 waves x 16 q-rows, KVBLK=64.
__global__ __launch_bounds__(512) void attn_kernel(const bf16_t* __restrict__ qkv,
                                                   const bf16_t* __restrict__ vT,
                                                   unsigned short* __restrict__ ob) {
  __shared__ bf16_t Kt[64 * 128];
  __shared__ bf16_t Vt[128 * 64];
  __shared__ bf16_t Pl[8 * 16 * 64];
  const int h  = blockIdx.x;
  const int qi = 15 - (int)blockIdx.y;
  const int qb = qi * 128;
  const int kh = h >> 2;
  const int tid = threadIdx.x, lane = tid & 63, w = tid >> 6;
  const int lg = lane >> 4, lr = lane & 15;
  const int qrow0 = qb + w * 16;

  bf16x8 qf[4];
  const bf16_t* qptr = qkv + (long)(qrow0 + lr) * QKVN + h * HDIM + lg * 8;
#pragma unroll
  for (int kk = 0; kk < 4; ++kk) qf[kk] = *(const bf16x8*)(qptr + kk * 32);

  const f32x4 z4 = {0.f, 0.f, 0.f, 0.f};
  f32x4 oacc[8];
#pragma unroll
  for (int c = 0; c < 8; ++c) oacc[c] = z4;
  float m[4]    = {-1e30f, -1e30f, -1e30f, -1e30f};
  float lsum[4] = {0.f, 0.f, 0.f, 0.f};

  char* KtB = (char*)Kt;
  char* VtB = (char*)Vt;
  char* PlB = (char*)Pl + w * 2048;
  const float scale = 0.08838834764831845f;
  const int ntiles = 2 * qi + 2;
  const int wqmax = qrow0 + 15;

  for (int t = 0; t < ntiles; ++t) {
    const int kv0 = t * 64;
    __syncthreads();
#pragma unroll
    for (int it = 0; it < 2; ++it) {
      int cch = tid + it * 512;
      int r = cch >> 4, c = cch & 15;
      const bf16_t* src = qkv + (long)(kv0 + r) * QKVN + 4096 + kh * HDIM
                          + ((c ^ (r & 7)) * 8);
      gload_lds16(src, KtB + cch * 16);
    }
#pragma unroll
    for (int it = 0; it < 2; ++it) {
      int cch = tid + it * 512;
      int hd = cch >> 3, c = cch & 7;
      const bf16_t* src = vT + ((long)kh * HDIM + hd) * S_LEN + kv0
                          + ((c ^ (hd & 7)) * 8);
      gload_lds16(src, VtB + cch * 16);
    }
    __syncthreads();
    if (kv0 > wqmax) continue;

    f32x4 sf[4];
#pragma unroll
    for (int f = 0; f < 4; ++f) {
      f32x4 a = z4;
      int n = f * 16 + lr;
      int rb = n * 256, sw = (n & 7) << 4;
#pragma unroll
      for (int kk = 0; kk < 4; ++kk) {
        bf16x8 kf = *(const bf16x8*)(KtB + rb + (((kk * 4 + lg) * 16) ^ sw));
        a = __builtin_amdgcn_mfma_f32_16x16x32_bf16(qf[kk], kf, a, 0, 0, 0);
      }
      sf[f] = a;
    }

    float sc_arr[4];
#pragma unroll
    for (int j = 0; j < 4; ++j) {
      int qrow = qrow0 + lg * 4 + j;
      float sv[4];
#pragma unroll
      for (int f = 0; f < 4; ++f) {
        float s = sf[f][j] * scale;
        if (kv0 + f * 16 + lr > qrow) s = -1e9f;
        sv[f] = s;
      }
      float mx = fmaxf(fmaxf(sv[0], sv[1]), fmaxf(sv[2], sv[3]));
      mx = fmaxf(mx, __shfl_xor(mx, 1));
      mx = fmaxf(mx, __shfl_xor(mx, 2));
      mx = fmaxf(mx, __shfl_xor(mx, 4));
      mx = fmaxf(mx, __shfl_xor(mx, 8));
      float mn = fmaxf(m[j], mx);
      float p[4];
#pragma unroll
      for (int f = 0; f < 4; ++f) p[f] = __expf(sv[f] - mn);
      float ps = (p[0] + p[1]) + (p[2] + p[3]);
      ps += __shfl_xor(ps, 1);
      ps += __shfl_xor(ps, 2);
      ps += __shfl_xor(ps, 4);
      ps += __shfl_xor(ps, 8);
      float sc = __expf(m[j] - mn);
      lsum[j] = lsum[j] * sc + ps;
      m[j] = mn;
      sc_arr[j] = sc;
      int row = lg * 4 + j;
      int swp = (row & 7) << 4;
#pragma unroll
      for (int f = 0; f < 4; ++f)
        *(unsigned short*)(PlB + row * 128 + (((f * 16 + lr) * 2) ^ swp)) = f2bf(p[f]);
    }
#pragma unroll
    for (int c = 0; c < 8; ++c)
#pragma unroll
      for (int j = 0; j < 4; ++j) oacc[c][j] *= sc_arr[j];

    bf16x8 pfr[2];
#pragma unroll
    for (int kk = 0; kk < 2; ++kk)
      pfr[kk] = *(const bf16x8*)(PlB + lr * 128 + (((kk * 4 + lg) * 16) ^ ((lr & 7) << 4)));
#pragma unroll
    for (int c = 0; c < 8; ++c) {
      int hd = c * 16 + lr;
      int rb = hd * 128, sw = (hd & 7) << 4;
#pragma unroll
      for (int kk = 0; kk < 2; ++kk) {
        bf16x8 vf = *(const bf16x8*)(VtB + rb + (((kk * 4 + lg) * 16) ^ sw));
        oacc[c] = __builtin_amdgcn_mfma_f32_16x16x32_bf16(pfr[kk], vf, oacc[c], 0, 0, 0);
      }
    }
  }

  float rl[4];
#pragma unroll
  for (int j = 0; j < 4; ++j) rl[j] = 1.f / lsum[j];
#pragma unroll
  for (int c = 0; c < 8; ++c)
#pragma unroll
    for (int j = 0; j < 4; ++j) {
      long row = qrow0 + lg * 4 + j;
      ob[row * 4096 + h * 128 + c * 16 + lr] = f2bf(oacc[c][j] * rl[j]);
    }
}

extern "C" void kernel_launch(void* const* d_in, const int* in_sizes, int n_in,
                              void* d_out, int out_size, void* d_ws, size_t ws_size,
                              hipStream_t stream) {
  const float* x  = (const float*)d_in[0];
  const float* wq = (const float*)d_in[1];
  const float* wk = (const float*)d_in[2];
  const float* wv = (const float*)d_in[3];
  const float* wo = (const float*)d_in[4];
  const float* fc = (const float*)d_in[5];
  const float* fs = (const float*)d_in[6];

  char* ws = (char*)d_ws;
  bf16_t* xb    = (bf16_t*)(ws + 0);          // 2048x4096 (dead after gemm1)
  bf16_t* wqkvb = (bf16_t*)(ws + 16777216);   // 6144x4096
  bf16_t* wob   = (bf16_t*)(ws + 67108864);   // 4096x4096
  bf16_t* qkv   = (bf16_t*)(ws + 100663296);  // 2048x6144
  bf16_t* ob    = (bf16_t*)(ws + 125829120);  // 2048x4096
  bf16_t* vT    = (bf16_t*)(ws + 0);          // 8x128x2048 (4 MB, reuses xb)

  cvt5_kernel<<<2048, 256, 0, stream>>>(x, wq, wk, wv, wo,
                                        (ushort4*)xb, (ushort4*)wqkvb, (ushort4*)wob);

  gemm8p<0><<<192, 512, 0, stream>>>(xb, wqkvb, qkv, 2048, 6144, 4096, 24);
  vtrans_kernel<<<dim3(8, 128), 256, 0, stream>>>(qkv, vT);
  rope_kernel<<<20480, 256, 0, stream>>>((unsigned int*)qkv, fc, fs);
  attn_kernel<<<dim3(32, 16), 512, 0, stream>>>(qkv, vT, (unsigned short*)ob);
  gemm8r<1><<<256, 512, 0, stream>>>(ob, wob, d_out, 2048, 4096, 4096, 32);
}

// Round 11
// 324.393 us; speedup vs baseline: 1.1088x; 1.0176x over previous
//
#include <hip/hip_runtime.h>
#include <hip/hip_bf16.h>
#include <stdint.h>

typedef __bf16 bf16_t;
typedef __attribute__((ext_vector_type(8))) __bf16 bf16x8;
typedef __attribute__((ext_vector_type(4))) float f32x4;
typedef __attribute__((ext_vector_type(8))) unsigned short u16x8;

#define S_LEN 2048
#define DIM   4096
#define QKVN  6144
#define NHEAD 32
#define HDIM  128

typedef __attribute__((address_space(1))) unsigned int as1_u32;
typedef __attribute__((address_space(3))) unsigned int as3_u32;

__device__ __forceinline__ unsigned short f2bf(float f) {
  unsigned u = __builtin_bit_cast(unsigned, f);
  u += 0x7fffu + ((u >> 16) & 1u);
  return (unsigned short)(u >> 16);
}

__device__ __forceinline__ void gload_lds16(const void* g, void* l) {
  __builtin_amdgcn_global_load_lds(
      (as1_u32*)(unsigned long long)(uintptr_t)g,
      (as3_u32*)(unsigned int)(uintptr_t)l,
      16, 0, 0);
}

// Fused f32->bf16 conversion for all 5 inputs (one launch, grid-stride).
__global__ __launch_bounds__(256) void cvt5_kernel(const float* __restrict__ x,
                                                   const float* __restrict__ wq,
                                                   const float* __restrict__ wk,
                                                   const float* __restrict__ wv,
                                                   const float* __restrict__ wo,
                                                   ushort4* __restrict__ xb,
                                                   ushort4* __restrict__ wqkvb,
                                                   ushort4* __restrict__ wob) {
  const long N0 = 2097152;           // x  : 2048*4096/4
  const long N1 = N0 + 4194304;      // wq : 4096*4096/4
  const long N2 = N1 + 1048576;      // wk
  const long N3 = N2 + 1048576;      // wv
  const long N4 = N3 + 4194304;      // wo
  long idx = (long)blockIdx.x * 256 + threadIdx.x;
  long stride = (long)gridDim.x * 256;
  for (long i = idx; i < N4; i += stride) {
    const float4* s; ushort4* d; long o;
    if (i < N0)      { s = (const float4*)x;  d = xb;              o = i; }
    else if (i < N1) { s = (const float4*)wq; d = wqkvb;           o = i - N0; }
    else if (i < N2) { s = (const float4*)wk; d = wqkvb + 4194304; o = i - N1; }
    else if (i < N3) { s = (const float4*)wv; d = wqkvb + 5242880; o = i - N2; }
    else             { s = (const float4*)wo; d = wob;             o = i - N3; }
    float4 v = s[o];
    ushort4 r;
    r.x = f2bf(v.x); r.y = f2bf(v.y); r.z = f2bf(v.z); r.w = f2bf(v.w);
    d[o] = r;
  }
}

// Shared swizzled LDS fragment read: chunk ^= (row&7), both sides.
__device__ __forceinline__ bf16x8 fld(const char* half, int row, int chunk) {
  return *(const bf16x8*)(half + row * 128 + ((chunk ^ (row & 7)) << 4));
}

// ---- 256x192 4-phase GEMM, BK=64, 8 waves (2M x 4N), wave tile 128x48 ---
// C(M,N) = A(M,K) * B(N,K)^T, bf16 out. Grid fills 256 CUs exactly for
// M=2048,N=6144. LDS 112KB: 2 dbuf x (A[256][64] 32KB + B[192][64] 24KB).
// Phases: P0 rd{A m0-1, B all}+stgA.h0(t+1,~d); P1 rd{A m2-3}+stgA.h1(~d);
// P2 rd{A m4-5}+stgB(t+2,d) [B(t) read-complete: every wave passed its P0
// lgkm(0) before issuing P2]; P3 rd{A m6-7}+vmcnt(3) [queue order:
// B(t+1),A(t+1) land, only B(t+2):3 left in flight].
template <int OUTF32>
__global__ __launch_bounds__(512, 2) void gemm8q(const bf16_t* __restrict__ A,
                                                 const bf16_t* __restrict__ B,
                                                 void* __restrict__ Cout,
                                                 int M, int N, int K, int nxt) {
  __shared__ char lds[114688];
  const int tid = threadIdx.x;
  const int lane = tid & 63, w = tid >> 6;
  const int wm = w >> 2, wn = w & 3;       // 2 M-waves x 4 N-waves
  const int lg = lane >> 4, lr = lane & 15;
  const int nwg = gridDim.x;
  const int orig = blockIdx.x;
  const int wgid = (orig & 7) * (nwg >> 3) + (orig >> 3);  // nwg % 8 == 0
  const int bx = wgid % nxt, by = wgid / nxt;
  const long rowA = (long)by * 256;
  const long rowB = (long)bx * 192;

  f32x4 acc[8][3];
  const f32x4 z4 = {0.f, 0.f, 0.f, 0.f};
#pragma unroll
  for (int i = 0; i < 8; ++i)
#pragma unroll
    for (int j = 0; j < 3; ++j) acc[i][j] = z4;

  const int r0 = tid >> 3, sl = tid & 7;
  const long xo  = (long)((sl ^ (r0 & 7)) << 3);
  const long aof = (rowA + r0) * (long)K + xo;
  const long bof = (rowB + r0) * (long)K + xo;
  const long j1  = (long)64 * K;
  const long h1  = (long)128 * K;
  const int ld0 = tid * 16, ld1 = (tid + 512) * 16, ld2 = (tid + 1024) * 16;

#define QSTG_A(K0, HALF, DBUF)                                                 \
  { char* hp = lds + (DBUF) * 57344 + (HALF) * 16384;                          \
    gload_lds16(A + aof + (HALF) * h1 + (K0),      hp + ld0);                  \
    gload_lds16(A + aof + (HALF) * h1 + j1 + (K0), hp + ld1); }
#define QSTG_B(K0, DBUF)                                                       \
  { char* bp = lds + (DBUF) * 57344 + 32768;                                   \
    gload_lds16(B + bof + (K0),          bp + ld0);                            \
    gload_lds16(B + bof + j1 + (K0),     bp + ld1);                            \
    gload_lds16(B + bof + 2 * j1 + (K0), bp + ld2); }

  const int nt = K >> 6;
  const int brow = wn * 48;

  // prologue: A(0)+B(0) -> dbuf0 (7 loads); B(1) -> dbuf1 (3); tile0 landed.
  QSTG_A(0, 0, 0); QSTG_A(0, 1, 0); QSTG_B(0, 0);
  QSTG_B(64, 1);
  asm volatile("s_waitcnt vmcnt(3)" ::: "memory");
  __builtin_amdgcn_s_barrier();

  bf16x8 af[8][2], bf_[3][2];

  for (int t = 0; t < nt; ++t) {
    const int d = t & 1;
    const char* Ah = lds + d * 57344 + wm * 16384;
    const char* Br = lds + d * 57344 + 32768;
    const int k1 = (t + 1) << 6, k2 = (t + 2) << 6;
    // ---- P0: read A m0-1 + B all; stage A.h0(t+1) ----
#pragma unroll
    for (int m = 0; m < 2; ++m) {
      af[m][0] = fld(Ah, m * 16 + lr, lg);
      af[m][1] = fld(Ah, m * 16 + lr, 4 + lg);
    }
#pragma unroll
    for (int n = 0; n < 3; ++n) {
      bf_[n][0] = fld(Br, brow + n * 16 + lr, lg);
      bf_[n][1] = fld(Br, brow + n * 16 + lr, 4 + lg);
    }
    if (t + 1 < nt) QSTG_A(k1, 0, d ^ 1);
    __builtin_amdgcn_s_barrier();
    asm volatile("s_waitcnt lgkmcnt(0)" ::: "memory");
    __builtin_amdgcn_sched_barrier(0);
    __builtin_amdgcn_s_setprio(1);
#pragma unroll
    for (int m = 0; m < 2; ++m)
#pragma unroll
      for (int n = 0; n < 3; ++n) {
        acc[m][n] = __builtin_amdgcn_mfma_f32_16x16x32_bf16(af[m][0], bf_[n][0], acc[m][n], 0, 0, 0);
        acc[m][n] = __builtin_amdgcn_mfma_f32_16x16x32_bf16(af[m][1], bf_[n][1], acc[m][n], 0, 0, 0);
      }
    __builtin_amdgcn_s_setprio(0);
    __builtin_amdgcn_s_barrier();
    // ---- P1: read A m2-3; stage A.h1(t+1) ----
#pragma unroll
    for (int m = 2; m < 4; ++m) {
      af[m][0] = fld(Ah, m * 16 + lr, lg);
      af[m][1] = fld(Ah, m * 16 + lr, 4 + lg);
    }
    if (t + 1 < nt) QSTG_A(k1, 1, d ^ 1);
    __builtin_amdgcn_s_barrier();
    asm volatile("s_waitcnt lgkmcnt(0)" ::: "memory");
    __builtin_amdgcn_sched_barrier(0);
    __builtin_amdgcn_s_setprio(1);
#pragma unroll
    for (int m = 2; m < 4; ++m)
#pragma unroll
      for (int n = 0; n < 3; ++n) {
        acc[m][n] = __builtin_amdgcn_mfma_f32_16x16x32_bf16(af[m][0], bf_[n][0], acc[m][n], 0, 0, 0);
        acc[m][n] = __builtin_amdgcn_mfma_f32_16x16x32_bf16(af[m][1], bf_[n][1], acc[m][n], 0, 0, 0);
      }
    __builtin_amdgcn_s_setprio(0);
    __builtin_amdgcn_s_barrier();
    // ---- P2: read A m4-5; stage B(t+2) ----
#pragma unroll
    for (int m = 4; m < 6; ++m) {
      af[m][0] = fld(Ah, m * 16 + lr, lg);
      af[m][1] = fld(Ah, m * 16 + lr, 4 + lg);
    }
    if (t + 2 < nt) QSTG_B(k2, d);
    __builtin_amdgcn_s_barrier();
    asm volatile("s_waitcnt lgkmcnt(0)" ::: "memory");
    __builtin_amdgcn_sched_barrier(0);
    __builtin_amdgcn_s_setprio(1);
#pragma unroll
    for (int m = 4; m < 6; ++m)
#pragma unroll
      for (int n = 0; n < 3; ++n) {
        acc[m][n] = __builtin_amdgcn_mfma_f32_16x16x32_bf16(af[m][0], bf_[n][0], acc[m][n], 0, 0, 0);
        acc[m][n] = __builtin_amdgcn_mfma_f32_16x16x32_bf16(af[m][1], bf_[n][1], acc[m][n], 0, 0, 0);
      }
    __builtin_amdgcn_s_setprio(0);
    __builtin_amdgcn_s_barrier();
    // ---- P3: read A m6-7; MFMA; vmcnt(3) ----
#pragma unroll
    for (int m = 6; m < 8; ++m) {
      af[m][0] = fld(Ah, m * 16 + lr, lg);
      af[m][1] = fld(Ah, m * 16 + lr, 4 + lg);
    }
    __builtin_amdgcn_s_barrier();
    asm volatile("s_waitcnt lgkmcnt(0)" ::: "memory");
    __builtin_amdgcn_sched_barrier(0);
    __builtin_amdgcn_s_setprio(1);
#pragma unroll
    for (int m = 6; m < 8; ++m)
#pragma unroll
      for (int n = 0; n < 3; ++n) {
        acc[m][n] = __builtin_amdgcn_mfma_f32_16x16x32_bf16(af[m][0], bf_[n][0], acc[m][n], 0, 0, 0);
        acc[m][n] = __builtin_amdgcn_mfma_f32_16x16x32_bf16(af[m][1], bf_[n][1], acc[m][n], 0, 0, 0);
      }
    __builtin_amdgcn_s_setprio(0);
    if (t + 2 < nt) {
      asm volatile("s_waitcnt vmcnt(3)" ::: "memory");
    } else {
      asm volatile("s_waitcnt vmcnt(0)" ::: "memory");
    }
    __builtin_amdgcn_s_barrier();
  }
#undef QSTG_A
#undef QSTG_B

  const long crow = rowA + wm * 128;
  const long ccol = rowB + wn * 48;
  if (OUTF32) {
    float* C = (float*)Cout;
#pragma unroll
    for (int mf = 0; mf < 8; ++mf)
#pragma unroll
      for (int j = 0; j < 4; ++j) {
        long row = crow + mf * 16 + lg * 4 + j;
        float* cp = C + row * N + ccol + lr;
#pragma unroll
        for (int nf = 0; nf < 3; ++nf) cp[nf * 16] = acc[mf][nf][j];
      }
  } else {
    unsigned short* C = (unsigned short*)Cout;
#pragma unroll
    for (int mf = 0; mf < 8; ++mf)
#pragma unroll
      for (int j = 0; j < 4; ++j) {
        long row = crow + mf * 16 + lg * 4 + j;
        unsigned short* cp = C + row * N + ccol + lr;
#pragma unroll
        for (int nf = 0; nf < 3; ++nf) cp[nf * 16] = f2bf(acc[mf][nf][j]);
      }
  }
}

// ---- 256x128 4-phase GEMM, BK=64, 8 waves (R10-verified for O-proj) -----
template <int OUTF32>
__global__ __launch_bounds__(512, 2) void gemm8r(const bf16_t* __restrict__ A,
                                                 const bf16_t* __restrict__ B,
                                                 void* __restrict__ Cout,
                                                 int M, int N, int K, int nxt) {
  __shared__ char lds[98304];
  const int tid = threadIdx.x;
  const int lane = tid & 63, w = tid >> 6;
  const int wm = w >> 1, wn = w & 1;       // 4 M-waves x 2 N-waves
  const int lg = lane >> 4, lr = lane & 15;
  const int nwg = gridDim.x;
  const int orig = blockIdx.x;
  const int wgid = (orig & 7) * (nwg >> 3) + (orig >> 3);  // nwg % 8 == 0
  const int bx = wgid % nxt, by = wgid / nxt;
  const long rowA = (long)by * 256;
  const long rowB = (long)bx * 128;

  f32x4 acc[4][4];
  const f32x4 z4 = {0.f, 0.f, 0.f, 0.f};
#pragma unroll
  for (int i = 0; i < 4; ++i)
#pragma unroll
    for (int j = 0; j < 4; ++j) acc[i][j] = z4;

  const int r0 = tid >> 3, sl = tid & 7;
  const long xo  = (long)((sl ^ (r0 & 7)) << 3);
  const long aof = (rowA + r0) * (long)K + xo;
  const long bof = (rowB + r0) * (long)K + xo;
  const long r64 = (long)64 * K;
  const int ld0 = tid * 16, ld1 = (tid + 512) * 16;

#define RSTG_A(K0, HALF, DBUF)                                                 \
  { char* ap = lds + (DBUF) * 49152 + (HALF) * 16384;                          \
    gload_lds16(A + aof + (HALF) * 2 * r64 + (K0),       ap + ld0);            \
    gload_lds16(A + aof + (HALF) * 2 * r64 + r64 + (K0), ap + ld1); }
#define RSTG_B(K0, DBUF)                                                       \
  { char* bp = lds + (DBUF) * 49152 + 32768;                                   \
    gload_lds16(B + bof + (K0),       bp + ld0);                               \
    gload_lds16(B + bof + r64 + (K0), bp + ld1); }

  const int nt = K >> 6;

  RSTG_A(0, 0, 0); RSTG_A(0, 1, 0); RSTG_B(0, 0);
  RSTG_B(64, 1);
  asm volatile("s_waitcnt vmcnt(2)" ::: "memory");
  __builtin_amdgcn_s_barrier();

  bf16x8 af[4][2], bf_[4][2];

  for (int t = 0; t < nt; ++t) {
    const int d = t & 1;
    const char* Ar = lds + d * 49152;
    const char* Br = Ar + 32768;
    const int arow = wm * 64, brow = wn * 64;
    const int k1 = (t + 1) << 6, k2 = (t + 2) << 6;
#pragma unroll
    for (int m = 0; m < 2; ++m) {
      af[m][0] = fld(Ar, arow + m * 16 + lr, lg);
      af[m][1] = fld(Ar, arow + m * 16 + lr, 4 + lg);
    }
#pragma unroll
    for (int n = 0; n < 2; ++n) {
      bf_[n][0] = fld(Br, brow + n * 16 + lr, lg);
      bf_[n][1] = fld(Br, brow + n * 16 + lr, 4 + lg);
    }
    if (t + 1 < nt) RSTG_A(k1, 0, d ^ 1);
    __builtin_amdgcn_s_barrier();
    asm volatile("s_waitcnt lgkmcnt(0)" ::: "memory");
    __builtin_amdgcn_sched_barrier(0);
    __builtin_amdgcn_s_setprio(1);
#pragma unroll
    for (int m = 0; m < 2; ++m)
#pragma unroll
      for (int n = 0; n < 2; ++n) {
        acc[m][n] = __builtin_amdgcn_mfma_f32_16x16x32_bf16(af[m][0], bf_[n][0], acc[m][n], 0, 0, 0);
        acc[m][n] = __builtin_amdgcn_mfma_f32_16x16x32_bf16(af[m][1], bf_[n][1], acc[m][n], 0, 0, 0);
      }
    __builtin_amdgcn_s_setprio(0);
    __builtin_amdgcn_s_barrier();
#pragma unroll
    for (int n = 2; n < 4; ++n) {
      bf_[n][0] = fld(Br, brow + n * 16 + lr, lg);
      bf_[n][1] = fld(Br, brow + n * 16 + lr, 4 + lg);
    }
    if (t + 1 < nt) RSTG_A(k1, 1, d ^ 1);
    __builtin_amdgcn_s_barrier();
    asm volatile("s_waitcnt lgkmcnt(0)" ::: "memory");
    __builtin_amdgcn_sched_barrier(0);
    __builtin_amdgcn_s_setprio(1);
#pragma unroll
    for (int m = 0; m < 2; ++m)
#pragma unroll
      for (int n = 2; n < 4; ++n) {
        acc[m][n] = __builtin_amdgcn_mfma_f32_16x16x32_bf16(af[m][0], bf_[n][0], acc[m][n], 0, 0, 0);
        acc[m][n] = __builtin_amdgcn_mfma_f32_16x16x32_bf16(af[m][1], bf_[n][1], acc[m][n], 0, 0, 0);
      }
    __builtin_amdgcn_s_setprio(0);
    __builtin_amdgcn_s_barrier();
#pragma unroll
    for (int m = 2; m < 4; ++m) {
      af[m][0] = fld(Ar, arow + m * 16 + lr, lg);
      af[m][1] = fld(Ar, arow + m * 16 + lr, 4 + lg);
    }
    if (t + 2 < nt) RSTG_B(k2, d);
    __builtin_amdgcn_s_barrier();
    asm volatile("s_waitcnt lgkmcnt(0)" ::: "memory");
    __builtin_amdgcn_sched_barrier(0);
    __builtin_amdgcn_s_setprio(1);
#pragma unroll
    for (int m = 2; m < 4; ++m)
#pragma unroll
      for (int n = 0; n < 2; ++n) {
        acc[m][n] = __builtin_amdgcn_mfma_f32_16x16x32_bf16(af[m][0], bf_[n][0], acc[m][n], 0, 0, 0);
        acc[m][n] = __builtin_amdgcn_mfma_f32_16x16x32_bf16(af[m][1], bf_[n][1], acc[m][n], 0, 0, 0);
      }
    __builtin_amdgcn_s_setprio(0);
    __builtin_amdgcn_s_barrier();
    __builtin_amdgcn_s_setprio(1);
#pragma unroll
    for (int m = 2; m < 4; ++m)
#pragma unroll
      for (int n = 2; n < 4; ++n) {
        acc[m][n] = __builtin_amdgcn_mfma_f32_16x16x32_bf16(af[m][0], bf_[n][0], acc[m][n], 0, 0, 0);
        acc[m][n] = __builtin_amdgcn_mfma_f32_16x16x32_bf16(af[m][1], bf_[n][1], acc[m][n], 0, 0, 0);
      }
    __builtin_amdgcn_s_setprio(0);
    if (t + 2 < nt) {
      asm volatile("s_waitcnt vmcnt(2)" ::: "memory");
    } else {
      asm volatile("s_waitcnt vmcnt(0)" ::: "memory");
    }
    __builtin_amdgcn_s_barrier();
  }
#undef RSTG_A
#undef RSTG_B

  const long crow = rowA + wm * 64;
  const long ccol = rowB + wn * 64;
  if (OUTF32) {
    float* C = (float*)Cout;
#pragma unroll
    for (int mf = 0; mf < 4; ++mf)
#pragma unroll
      for (int j = 0; j < 4; ++j) {
        long row = crow + mf * 16 + lg * 4 + j;
        float* cp = C + row * N + ccol + lr;
#pragma unroll
        for (int nf = 0; nf < 4; ++nf) cp[nf * 16] = acc[mf][nf][j];
      }
  } else {
    unsigned short* C = (unsigned short*)Cout;
#pragma unroll
    for (int mf = 0; mf < 4; ++mf)
#pragma unroll
      for (int j = 0; j < 4; ++j) {
        long row = crow + mf * 16 + lg * 4 + j;
        unsigned short* cp = C + row * N + ccol + lr;
#pragma unroll
        for (int nf = 0; nf < 4; ++nf) cp[nf * 16] = f2bf(acc[mf][nf][j]);
      }
  }
}

// In-place RoPE on bf16 qkv buffer (q heads 0..31, k heads 32..39).
__global__ __launch_bounds__(256) void rope_kernel(unsigned int* __restrict__ qkv32,
                                                   const float* __restrict__ cosb,
                                                   const float* __restrict__ sinb) {
  int t = blockIdx.x * 256 + threadIdx.x;
  int i  = t & 63;
  int sh = t >> 6;
  int hh = sh % 40;
  int s  = sh / 40;
  int col2 = (hh < 32) ? (hh * 64 + i) : (2048 + (hh - 32) * 64 + i);
  unsigned int* p = qkv32 + (long)s * (QKVN / 2) + col2;
  unsigned int v = *p;
  float tr = __builtin_bit_cast(float, (v & 0xffffu) << 16);
  float ti = __builtin_bit_cast(float, v & 0xffff0000u);
  float c  = cosb[s * 64 + i];
  float sn = sinb[s * 64 + i];
  float orr = tr * c - ti * sn;
  float oi  = tr * sn + ti * c;
  *p = (unsigned int)f2bf(orr) | ((unsigned int)f2bf(oi) << 16);
}

// V transpose: vT[kh][hd][s] from qkv[s][5120 + kh*128 + hd].
__global__ __launch_bounds__(256) void vtrans_kernel(const bf16_t* __restrict__ qkv,
                                                     bf16_t* __restrict__ vT) {
  const int kh = blockIdx.x;
  const int hd = threadIdx.x & 127;
  const int s0 = blockIdx.y * 16 + (threadIdx.x >> 7) * 8;
  u16x8 v;
#pragma unroll
  for (int e = 0; e < 8; ++e)
    v[e] = *(const unsigned short*)(qkv + (long)(s0 + e) * QKVN + 5120 + kh * HDIM + hd);
  *(u16x8*)(vT + ((long)kh * HDIM + hd) * S_LEN + s0) = v;
}

// Flash attention: block = (128 q-rows, 1 head), 8 waves x 16 q-rows, KVBLK=64.
__global__ __launch_bounds__(512) void attn_kernel(const bf16_t* __restrict__ qkv,
                                                   const bf16_t* __restrict__ vT,
                                                   unsigned short* __restrict__ ob) {
  __shared__ bf16_t Kt[64 * 128];
  __shared__ bf16_t Vt[128 * 64];
  __shared__ bf16_t Pl[8 * 16 * 64];
  const int h  = blockIdx.x;
  const int qi = 15 - (int)blockIdx.y;
  const int qb = qi * 128;
  const int kh = h >> 2;
  const int tid = threadIdx.x, lane = tid & 63, w = tid >> 6;
  const int lg = lane >> 4, lr = lane & 15;
  const int qrow0 = qb + w * 16;

  bf16x8 qf[4];
  const bf16_t* qptr = qkv + (long)(qrow0 + lr) * QKVN + h * HDIM + lg * 8;
#pragma unroll
  for (int kk = 0; kk < 4; ++kk) qf[kk] = *(const bf16x8*)(qptr + kk * 32);

  const f32x4 z4 = {0.f, 0.f, 0.f, 0.f};
  f32x4 oacc[8];
#pragma unroll
  for (int c = 0; c < 8; ++c) oacc[c] = z4;
  float m[4]    = {-1e30f, -1e30f, -1e30f, -1e30f};
  float lsum[4] = {0.f, 0.f, 0.f, 0.f};

  char* KtB = (char*)Kt;
  char* VtB = (char*)Vt;
  char* PlB = (char*)Pl + w * 2048;
  const float scale = 0.08838834764831845f;
  const int ntiles = 2 * qi + 2;
  const int wqmax = qrow0 + 15;

  for (int t = 0; t < ntiles; ++t) {
    const int kv0 = t * 64;
    __syncthreads();
#pragma unroll
    for (int it = 0; it < 2; ++it) {
      int cch = tid + it * 512;
      int r = cch >> 4, c = cch & 15;
      const bf16_t* src = qkv + (long)(kv0 + r) * QKVN + 4096 + kh * HDIM
                          + ((c ^ (r & 7)) * 8);
      gload_lds16(src, KtB + cch * 16);
    }
#pragma unroll
    for (int it = 0; it < 2; ++it) {
      int cch = tid + it * 512;
      int hd = cch >> 3, c = cch & 7;
      const bf16_t* src = vT + ((long)kh * HDIM + hd) * S_LEN + kv0
                          + ((c ^ (hd & 7)) * 8);
      gload_lds16(src, VtB + cch * 16);
    }
    __syncthreads();
    if (kv0 > wqmax) continue;

    f32x4 sf[4];
#pragma unroll
    for (int f = 0; f < 4; ++f) {
      f32x4 a = z4;
      int n = f * 16 + lr;
      int rb = n * 256, sw = (n & 7) << 4;
#pragma unroll
      for (int kk = 0; kk < 4; ++kk) {
        bf16x8 kf = *(const bf16x8*)(KtB + rb + (((kk * 4 + lg) * 16) ^ sw));
        a = __builtin_amdgcn_mfma_f32_16x16x32_bf16(qf[kk], kf, a, 0, 0, 0);
      }
      sf[f] = a;
    }

    float sc_arr[4];
#pragma unroll
    for (int j = 0; j < 4; ++j) {
      int qrow = qrow0 + lg * 4 + j;
      float sv[4];
#pragma unroll
      for (int f = 0; f < 4; ++f) {
        float s = sf[f][j] * scale;
        if (kv0 + f * 16 + lr > qrow) s = -1e9f;
        sv[f] = s;
      }
      float mx = fmaxf(fmaxf(sv[0], sv[1]), fmaxf(sv[2], sv[3]));
      mx = fmaxf(mx, __shfl_xor(mx, 1));
      mx = fmaxf(mx, __shfl_xor(mx, 2));
      mx = fmaxf(mx, __shfl_xor(mx, 4));
      mx = fmaxf(mx, __shfl_xor(mx, 8));
      float mn = fmaxf(m[j], mx);
      float p[4];
#pragma unroll
      for (int f = 0; f < 4; ++f) p[f] = __expf(sv[f] - mn);
      float ps = (p[0] + p[1]) + (p[2] + p[3]);
      ps += __shfl_xor(ps, 1);
      ps += __shfl_xor(ps, 2);
      ps += __shfl_xor(ps, 4);
      ps += __shfl_xor(ps, 8);
      float sc = __expf(m[j] - mn);
      lsum[j] = lsum[j] * sc + ps;
      m[j] = mn;
      sc_arr[j] = sc;
      int row = lg * 4 + j;
      int swp = (row & 7) << 4;
#pragma unroll
      for (int f = 0; f < 4; ++f)
        *(unsigned short*)(PlB + row * 128 + (((f * 16 + lr) * 2) ^ swp)) = f2bf(p[f]);
    }
#pragma unroll
    for (int c = 0; c < 8; ++c)
#pragma unroll
      for (int j = 0; j < 4; ++j) oacc[c][j] *= sc_arr[j];

    bf16x8 pfr[2];
#pragma unroll
    for (int kk = 0; kk < 2; ++kk)
      pfr[kk] = *(const bf16x8*)(PlB + lr * 128 + (((kk * 4 + lg) * 16) ^ ((lr & 7) << 4)));
#pragma unroll
    for (int c = 0; c < 8; ++c) {
      int hd = c * 16 + lr;
      int rb = hd * 128, sw = (hd & 7) << 4;
#pragma unroll
      for (int kk = 0; kk < 2; ++kk) {
        bf16x8 vf = *(const bf16x8*)(VtB + rb + (((kk * 4 + lg) * 16) ^ sw));
        oacc[c] = __builtin_amdgcn_mfma_f32_16x16x32_bf16(pfr[kk], vf, oacc[c], 0, 0, 0);
      }
    }
  }

  float rl[4];
#pragma unroll
  for (int j = 0; j < 4; ++j) rl[j] = 1.f / lsum[j];
#pragma unroll
  for (int c = 0; c < 8; ++c)
#pragma unroll
    for (int j = 0; j < 4; ++j) {
      long row = qrow0 + lg * 4 + j;
      ob[row * 4096 + h * 128 + c * 16 + lr] = f2bf(oacc[c][j] * rl[j]);
    }
}

extern "C" void kernel_launch(void* const* d_in, const int* in_sizes, int n_in,
                              void* d_out, int out_size, void* d_ws, size_t ws_size,
                              hipStream_t stream) {
  const float* x  = (const float*)d_in[0];
  const float* wq = (const float*)d_in[1];
  const float* wk = (const float*)d_in[2];
  const float* wv = (const float*)d_in[3];
  const float* wo = (const float*)d_in[4];
  const float* fc = (const float*)d_in[5];
  const float* fs = (const float*)d_in[6];

  char* ws = (char*)d_ws;
  bf16_t* xb    = (bf16_t*)(ws + 0);          // 2048x4096 (dead after gemm1)
  bf16_t* wqkvb = (bf16_t*)(ws + 16777216);   // 6144x4096
  bf16_t* wob   = (bf16_t*)(ws + 67108864);   // 4096x4096
  bf16_t* qkv   = (bf16_t*)(ws + 100663296);  // 2048x6144
  bf16_t* ob    = (bf16_t*)(ws + 125829120);  // 2048x4096
  bf16_t* vT    = (bf16_t*)(ws + 0);          // 8x128x2048 (4 MB, reuses xb)

  cvt5_kernel<<<2048, 256, 0, stream>>>(x, wq, wk, wv, wo,
                                        (ushort4*)xb, (ushort4*)wqkvb, (ushort4*)wob);

  gemm8q<0><<<256, 512, 0, stream>>>(xb, wqkvb, qkv, 2048, 6144, 4096, 32);
  vtrans_kernel<<<dim3(8, 128), 256, 0, stream>>>(qkv, vT);
  rope_kernel<<<20480, 256, 0, stream>>>((unsigned int*)qkv, fc, fs);
  attn_kernel<<<dim3(32, 16), 512, 0, stream>>>(qkv, vT, (unsigned short*)ob);
  gemm8r<1><<<256, 512, 0, stream>>>(ob, wob, d_out, 2048, 4096, 4096, 32);
}

// Round 12
// 320.919 us; speedup vs baseline: 1.1208x; 1.0108x over previous
//
#include <hip/hip_runtime.h>
#include <hip/hip_bf16.h>
#include <stdint.h>

typedef __bf16 bf16_t;
typedef __attribute__((ext_vector_type(8))) __bf16 bf16x8;
typedef __attribute__((ext_vector_type(4))) float f32x4;
typedef __attribute__((ext_vector_type(8))) unsigned short u16x8;

#define S_LEN 2048
#define DIM   4096
#define QKVN  6144
#define NHEAD 32
#define HDIM  128

typedef __attribute__((address_space(1))) unsigned int as1_u32;
typedef __attribute__((address_space(3))) unsigned int as3_u32;

__device__ __forceinline__ unsigned short f2bf(float f) {
  unsigned u = __builtin_bit_cast(unsigned, f);
  u += 0x7fffu + ((u >> 16) & 1u);
  return (unsigned short)(u >> 16);
}

__device__ __forceinline__ void gload_lds16(const void* g, void* l) {
  __builtin_amdgcn_global_load_lds(
      (as1_u32*)(unsigned long long)(uintptr_t)g,
      (as3_u32*)(unsigned int)(uintptr_t)l,
      16, 0, 0);
}

// Fused f32->bf16 conversion for all 5 inputs (one launch, grid-stride).
__global__ __launch_bounds__(256) void cvt5_kernel(const float* __restrict__ x,
                                                   const float* __restrict__ wq,
                                                   const float* __restrict__ wk,
                                                   const float* __restrict__ wv,
                                                   const float* __restrict__ wo,
                                                   ushort4* __restrict__ xb,
                                                   ushort4* __restrict__ wqkvb,
                                                   ushort4* __restrict__ wob) {
  const long N0 = 2097152;           // x  : 2048*4096/4
  const long N1 = N0 + 4194304;      // wq : 4096*4096/4
  const long N2 = N1 + 1048576;      // wk
  const long N3 = N2 + 1048576;      // wv
  const long N4 = N3 + 4194304;      // wo
  long idx = (long)blockIdx.x * 256 + threadIdx.x;
  long stride = (long)gridDim.x * 256;
  for (long i = idx; i < N4; i += stride) {
    const float4* s; ushort4* d; long o;
    if (i < N0)      { s = (const float4*)x;  d = xb;              o = i; }
    else if (i < N1) { s = (const float4*)wq; d = wqkvb;           o = i - N0; }
    else if (i < N2) { s = (const float4*)wk; d = wqkvb + 4194304; o = i - N1; }
    else if (i < N3) { s = (const float4*)wv; d = wqkvb + 5242880; o = i - N2; }
    else             { s = (const float4*)wo; d = wob;             o = i - N3; }
    float4 v = s[o];
    ushort4 r;
    r.x = f2bf(v.x); r.y = f2bf(v.y); r.z = f2bf(v.z); r.w = f2bf(v.w);
    d[o] = r;
  }
}

// Shared swizzled LDS fragment read: chunk ^= (row&7), both sides.
__device__ __forceinline__ bf16x8 fld(const char* half, int row, int chunk) {
  return *(const bf16x8*)(half + row * 128 + ((chunk ^ (row & 7)) << 4));
}

// ---- 256x192 4-phase GEMM, BK=64, 8 waves (2M x 4N) (R11: QKV 109us) ----
template <int OUTF32>
__global__ __launch_bounds__(512, 2) void gemm8q(const bf16_t* __restrict__ A,
                                                 const bf16_t* __restrict__ B,
                                                 void* __restrict__ Cout,
                                                 int M, int N, int K, int nxt) {
  __shared__ char lds[114688];
  const int tid = threadIdx.x;
  const int lane = tid & 63, w = tid >> 6;
  const int wm = w >> 2, wn = w & 3;       // 2 M-waves x 4 N-waves
  const int lg = lane >> 4, lr = lane & 15;
  const int nwg = gridDim.x;
  const int orig = blockIdx.x;
  const int wgid = (orig & 7) * (nwg >> 3) + (orig >> 3);  // nwg % 8 == 0
  const int bx = wgid % nxt, by = wgid / nxt;
  const long rowA = (long)by * 256;
  const long rowB = (long)bx * 192;

  f32x4 acc[8][3];
  const f32x4 z4 = {0.f, 0.f, 0.f, 0.f};
#pragma unroll
  for (int i = 0; i < 8; ++i)
#pragma unroll
    for (int j = 0; j < 3; ++j) acc[i][j] = z4;

  const int r0 = tid >> 3, sl = tid & 7;
  const long xo  = (long)((sl ^ (r0 & 7)) << 3);
  const long aof = (rowA + r0) * (long)K + xo;
  const long bof = (rowB + r0) * (long)K + xo;
  const long j1  = (long)64 * K;
  const long h1  = (long)128 * K;
  const int ld0 = tid * 16, ld1 = (tid + 512) * 16, ld2 = (tid + 1024) * 16;

#define QSTG_A(K0, HALF, DBUF)                                                 \
  { char* hp = lds + (DBUF) * 57344 + (HALF) * 16384;                          \
    gload_lds16(A + aof + (HALF) * h1 + (K0),      hp + ld0);                  \
    gload_lds16(A + aof + (HALF) * h1 + j1 + (K0), hp + ld1); }
#define QSTG_B(K0, DBUF)                                                       \
  { char* bp = lds + (DBUF) * 57344 + 32768;                                   \
    gload_lds16(B + bof + (K0),          bp + ld0);                            \
    gload_lds16(B + bof + j1 + (K0),     bp + ld1);                            \
    gload_lds16(B + bof + 2 * j1 + (K0), bp + ld2); }

  const int nt = K >> 6;
  const int brow = wn * 48;

  QSTG_A(0, 0, 0); QSTG_A(0, 1, 0); QSTG_B(0, 0);
  QSTG_B(64, 1);
  asm volatile("s_waitcnt vmcnt(3)" ::: "memory");
  __builtin_amdgcn_s_barrier();

  bf16x8 af[8][2], bf_[3][2];

  for (int t = 0; t < nt; ++t) {
    const int d = t & 1;
    const char* Ah = lds + d * 57344 + wm * 16384;
    const char* Br = lds + d * 57344 + 32768;
    const int k1 = (t + 1) << 6, k2 = (t + 2) << 6;
#pragma unroll
    for (int m = 0; m < 2; ++m) {
      af[m][0] = fld(Ah, m * 16 + lr, lg);
      af[m][1] = fld(Ah, m * 16 + lr, 4 + lg);
    }
#pragma unroll
    for (int n = 0; n < 3; ++n) {
      bf_[n][0] = fld(Br, brow + n * 16 + lr, lg);
      bf_[n][1] = fld(Br, brow + n * 16 + lr, 4 + lg);
    }
    if (t + 1 < nt) QSTG_A(k1, 0, d ^ 1);
    __builtin_amdgcn_s_barrier();
    asm volatile("s_waitcnt lgkmcnt(0)" ::: "memory");
    __builtin_amdgcn_sched_barrier(0);
    __builtin_amdgcn_s_setprio(1);
#pragma unroll
    for (int m = 0; m < 2; ++m)
#pragma unroll
      for (int n = 0; n < 3; ++n) {
        acc[m][n] = __builtin_amdgcn_mfma_f32_16x16x32_bf16(af[m][0], bf_[n][0], acc[m][n], 0, 0, 0);
        acc[m][n] = __builtin_amdgcn_mfma_f32_16x16x32_bf16(af[m][1], bf_[n][1], acc[m][n], 0, 0, 0);
      }
    __builtin_amdgcn_s_setprio(0);
    __builtin_amdgcn_s_barrier();
#pragma unroll
    for (int m = 2; m < 4; ++m) {
      af[m][0] = fld(Ah, m * 16 + lr, lg);
      af[m][1] = fld(Ah, m * 16 + lr, 4 + lg);
    }
    if (t + 1 < nt) QSTG_A(k1, 1, d ^ 1);
    __builtin_amdgcn_s_barrier();
    asm volatile("s_waitcnt lgkmcnt(0)" ::: "memory");
    __builtin_amdgcn_sched_barrier(0);
    __builtin_amdgcn_s_setprio(1);
#pragma unroll
    for (int m = 2; m < 4; ++m)
#pragma unroll
      for (int n = 0; n < 3; ++n) {
        acc[m][n] = __builtin_amdgcn_mfma_f32_16x16x32_bf16(af[m][0], bf_[n][0], acc[m][n], 0, 0, 0);
        acc[m][n] = __builtin_amdgcn_mfma_f32_16x16x32_bf16(af[m][1], bf_[n][1], acc[m][n], 0, 0, 0);
      }
    __builtin_amdgcn_s_setprio(0);
    __builtin_amdgcn_s_barrier();
#pragma unroll
    for (int m = 4; m < 6; ++m) {
      af[m][0] = fld(Ah, m * 16 + lr, lg);
      af[m][1] = fld(Ah, m * 16 + lr, 4 + lg);
    }
    if (t + 2 < nt) QSTG_B(k2, d);
    __builtin_amdgcn_s_barrier();
    asm volatile("s_waitcnt lgkmcnt(0)" ::: "memory");
    __builtin_amdgcn_sched_barrier(0);
    __builtin_amdgcn_s_setprio(1);
#pragma unroll
    for (int m = 4; m < 6; ++m)
#pragma unroll
      for (int n = 0; n < 3; ++n) {
        acc[m][n] = __builtin_amdgcn_mfma_f32_16x16x32_bf16(af[m][0], bf_[n][0], acc[m][n], 0, 0, 0);
        acc[m][n] = __builtin_amdgcn_mfma_f32_16x16x32_bf16(af[m][1], bf_[n][1], acc[m][n], 0, 0, 0);
      }
    __builtin_amdgcn_s_setprio(0);
    __builtin_amdgcn_s_barrier();
#pragma unroll
    for (int m = 6; m < 8; ++m) {
      af[m][0] = fld(Ah, m * 16 + lr, lg);
      af[m][1] = fld(Ah, m * 16 + lr, 4 + lg);
    }
    __builtin_amdgcn_s_barrier();
    asm volatile("s_waitcnt lgkmcnt(0)" ::: "memory");
    __builtin_amdgcn_sched_barrier(0);
    __builtin_amdgcn_s_setprio(1);
#pragma unroll
    for (int m = 6; m < 8; ++m)
#pragma unroll
      for (int n = 0; n < 3; ++n) {
        acc[m][n] = __builtin_amdgcn_mfma_f32_16x16x32_bf16(af[m][0], bf_[n][0], acc[m][n], 0, 0, 0);
        acc[m][n] = __builtin_amdgcn_mfma_f32_16x16x32_bf16(af[m][1], bf_[n][1], acc[m][n], 0, 0, 0);
      }
    __builtin_amdgcn_s_setprio(0);
    if (t + 2 < nt) {
      asm volatile("s_waitcnt vmcnt(3)" ::: "memory");
    } else {
      asm volatile("s_waitcnt vmcnt(0)" ::: "memory");
    }
    __builtin_amdgcn_s_barrier();
  }
#undef QSTG_A
#undef QSTG_B

  const long crow = rowA + wm * 128;
  const long ccol = rowB + wn * 48;
  unsigned short* C = (unsigned short*)Cout;
#pragma unroll
  for (int mf = 0; mf < 8; ++mf)
#pragma unroll
    for (int j = 0; j < 4; ++j) {
      long row = crow + mf * 16 + lg * 4 + j;
      unsigned short* cp = C + row * N + ccol + lr;
#pragma unroll
      for (int nf = 0; nf < 3; ++nf) cp[nf * 16] = f2bf(acc[mf][nf][j]);
    }
}

// ---- 256x128 2-phase GEMM, BK=64, 8 waves (4M x 2N), 16 MFMA/phase ------
// A,B triple-buffered (LDS 3x32K + 3x16K = 144KB), stage depth t+2,
// vmcnt(6) at tile end (FIFO: A(t+1)+B(t+1) drained, t+2's 6 in flight).
// Phases: P0 rd{A all, B n0-1}+stgA(t+2); P1 rd{B n2-3}+stgB(t+2).
template <int OUTF32>
__global__ __launch_bounds__(512, 2) void gemm2p(const bf16_t* __restrict__ A,
                                                 const bf16_t* __restrict__ B,
                                                 void* __restrict__ Cout,
                                                 int M, int N, int K, int nxt) {
  __shared__ char lds[147456];
  const int tid = threadIdx.x;
  const int lane = tid & 63, w = tid >> 6;
  const int wm = w >> 1, wn = w & 1;       // 4 M-waves x 2 N-waves, 64x64
  const int lg = lane >> 4, lr = lane & 15;
  const int nwg = gridDim.x;
  const int orig = blockIdx.x;
  const int wgid = (orig & 7) * (nwg >> 3) + (orig >> 3);  // nwg % 8 == 0
  const int bx = wgid % nxt, by = wgid / nxt;
  const long rowA = (long)by * 256;
  const long rowB = (long)bx * 128;

  f32x4 acc[4][4];
  const f32x4 z4 = {0.f, 0.f, 0.f, 0.f};
#pragma unroll
  for (int i = 0; i < 4; ++i)
#pragma unroll
    for (int j = 0; j < 4; ++j) acc[i][j] = z4;

  const int r0 = tid >> 3, sl = tid & 7;
  const long xo  = (long)((sl ^ (r0 & 7)) << 3);
  const long aof = (rowA + r0) * (long)K + xo;
  const long bof = (rowB + r0) * (long)K + xo;
  const long r64 = (long)64 * K;

#define PSTG_A(K0, BUF)                                                        \
  { char* ap = lds + (BUF) * 32768;                                            \
    gload_lds16(A + aof + (K0),           ap + tid * 16);                      \
    gload_lds16(A + aof + r64 + (K0),     ap + (tid + 512) * 16);              \
    gload_lds16(A + aof + 2 * r64 + (K0), ap + (tid + 1024) * 16);             \
    gload_lds16(A + aof + 3 * r64 + (K0), ap + (tid + 1536) * 16); }
#define PSTG_B(K0, BUF)                                                        \
  { char* bp = lds + 98304 + (BUF) * 16384;                                    \
    gload_lds16(B + bof + (K0),       bp + tid * 16);                          \
    gload_lds16(B + bof + r64 + (K0), bp + (tid + 512) * 16); }

  const int nt = K >> 6;

  // prologue: A(0),B(0),A(1),B(1); wait tile0 (first 6 of 12).
  PSTG_A(0, 0); PSTG_B(0, 0); PSTG_A(64, 1); PSTG_B(64, 1);
  asm volatile("s_waitcnt vmcnt(6)" ::: "memory");
  __builtin_amdgcn_s_barrier();

  bf16x8 af[4][2], bf_[4][2];

  for (int t = 0; t < nt; ++t) {
    const int b3 = t % 3, s3 = (t + 2) % 3;
    const char* Ab = lds + b3 * 32768;
    const char* Bb = lds + 98304 + b3 * 16384;
    const int arow = wm * 64, brow = wn * 64;
    const int k2 = (t + 2) << 6;
    // ---- P0: read A all + B n0-1; stage A(t+2) ----
#pragma unroll
    for (int m = 0; m < 4; ++m) {
      af[m][0] = fld(Ab, arow + m * 16 + lr, lg);
      af[m][1] = fld(Ab, arow + m * 16 + lr, 4 + lg);
    }
#pragma unroll
    for (int n = 0; n < 2; ++n) {
      bf_[n][0] = fld(Bb, brow + n * 16 + lr, lg);
      bf_[n][1] = fld(Bb, brow + n * 16 + lr, 4 + lg);
    }
    if (t + 2 < nt) PSTG_A(k2, s3);
    __builtin_amdgcn_s_barrier();
    asm volatile("s_waitcnt lgkmcnt(0)" ::: "memory");
    __builtin_amdgcn_sched_barrier(0);
    __builtin_amdgcn_s_setprio(1);
#pragma unroll
    for (int m = 0; m < 4; ++m)
#pragma unroll
      for (int n = 0; n < 2; ++n) {
        acc[m][n] = __builtin_amdgcn_mfma_f32_16x16x32_bf16(af[m][0], bf_[n][0], acc[m][n], 0, 0, 0);
        acc[m][n] = __builtin_amdgcn_mfma_f32_16x16x32_bf16(af[m][1], bf_[n][1], acc[m][n], 0, 0, 0);
      }
    __builtin_amdgcn_s_setprio(0);
    __builtin_amdgcn_s_barrier();
    // ---- P1: read B n2-3; stage B(t+2); vmcnt(6) ----
#pragma unroll
    for (int n = 2; n < 4; ++n) {
      bf_[n][0] = fld(Bb, brow + n * 16 + lr, lg);
      bf_[n][1] = fld(Bb, brow + n * 16 + lr, 4 + lg);
    }
    if (t + 2 < nt) PSTG_B(k2, s3);
    __builtin_amdgcn_s_barrier();
    asm volatile("s_waitcnt lgkmcnt(0)" ::: "memory");
    __builtin_amdgcn_sched_barrier(0);
    __builtin_amdgcn_s_setprio(1);
#pragma unroll
    for (int m = 0; m < 4; ++m)
#pragma unroll
      for (int n = 2; n < 4; ++n) {
        acc[m][n] = __builtin_amdgcn_mfma_f32_16x16x32_bf16(af[m][0], bf_[n][0], acc[m][n], 0, 0, 0);
        acc[m][n] = __builtin_amdgcn_mfma_f32_16x16x32_bf16(af[m][1], bf_[n][1], acc[m][n], 0, 0, 0);
      }
    __builtin_amdgcn_s_setprio(0);
    if (t + 2 < nt) {
      asm volatile("s_waitcnt vmcnt(6)" ::: "memory");
    } else {
      asm volatile("s_waitcnt vmcnt(0)" ::: "memory");
    }
    __builtin_amdgcn_s_barrier();
  }
#undef PSTG_A
#undef PSTG_B

  const long crow = rowA + wm * 64;
  const long ccol = rowB + wn * 64;
  if (OUTF32) {
    float* C = (float*)Cout;
#pragma unroll
    for (int mf = 0; mf < 4; ++mf)
#pragma unroll
      for (int j = 0; j < 4; ++j) {
        long row = crow + mf * 16 + lg * 4 + j;
        float* cp = C + row * N + ccol + lr;
#pragma unroll
        for (int nf = 0; nf < 4; ++nf) cp[nf * 16] = acc[mf][nf][j];
      }
  } else {
    unsigned short* C = (unsigned short*)Cout;
#pragma unroll
    for (int mf = 0; mf < 4; ++mf)
#pragma unroll
      for (int j = 0; j < 4; ++j) {
        long row = crow + mf * 16 + lg * 4 + j;
        unsigned short* cp = C + row * N + ccol + lr;
#pragma unroll
        for (int nf = 0; nf < 4; ++nf) cp[nf * 16] = f2bf(acc[mf][nf][j]);
      }
  }
}

// In-place RoPE on bf16 qkv buffer (q heads 0..31, k heads 32..39).
__global__ __launch_bounds__(256) void rope_kernel(unsigned int* __restrict__ qkv32,
                                                   const float* __restrict__ cosb,
                                                   const float* __restrict__ sinb) {
  int t = blockIdx.x * 256 + threadIdx.x;
  int i  = t & 63;
  int sh = t >> 6;
  int hh = sh % 40;
  int s  = sh / 40;
  int col2 = (hh < 32) ? (hh * 64 + i) : (2048 + (hh - 32) * 64 + i);
  unsigned int* p = qkv32 + (long)s * (QKVN / 2) + col2;
  unsigned int v = *p;
  float tr = __builtin_bit_cast(float, (v & 0xffffu) << 16);
  float ti = __builtin_bit_cast(float, v & 0xffff0000u);
  float c  = cosb[s * 64 + i];
  float sn = sinb[s * 64 + i];
  float orr = tr * c - ti * sn;
  float oi  = tr * sn + ti * c;
  *p = (unsigned int)f2bf(orr) | ((unsigned int)f2bf(oi) << 16);
}

// V transpose: vT[kh][hd][s] from qkv[s][5120 + kh*128 + hd].
__global__ __launch_bounds__(256) void vtrans_kernel(const bf16_t* __restrict__ qkv,
                                                     bf16_t* __restrict__ vT) {
  const int kh = blockIdx.x;
  const int hd = threadIdx.x & 127;
  const int s0 = blockIdx.y * 16 + (threadIdx.x >> 7) * 8;
  u16x8 v;
#pragma unroll
  for (int e = 0; e < 8; ++e)
    v[e] = *(const unsigned short*)(qkv + (long)(s0 + e) * QKVN + 5120 + kh * HDIM + hd);
  *(u16x8*)(vT + ((long)kh * HDIM + hd) * S_LEN + s0) = v;
}

// Flash attention: block = (128 q-rows, 1 head), 8 waves x 16 q-rows, KVBLK=64.
// Softmax in exp2 domain (raw v_exp_f32); wave-uniform mask skip for
// non-diagonal tiles; defer-max (T13, THR=0) skips oacc rescale.
__global__ __launch_bounds__(512) void attn_kernel(const bf16_t* __restrict__ qkv,
                                                   const bf16_t* __restrict__ vT,
                                                   unsigned short* __restrict__ ob) {
  __shared__ bf16_t Kt[64 * 128];
  __shared__ bf16_t Vt[128 * 64];
  __shared__ bf16_t Pl[8 * 16 * 64];
  const int h  = blockIdx.x;
  const int qi = 15 - (int)blockIdx.y;
  const int qb = qi * 128;
  const int kh = h >> 2;
  const int tid = threadIdx.x, lane = tid & 63, w = tid >> 6;
  const int lg = lane >> 4, lr = lane & 15;
  const int qrow0 = qb + w * 16;

  bf16x8 qf[4];
  const bf16_t* qptr = qkv + (long)(qrow0 + lr) * QKVN + h * HDIM + lg * 8;
#pragma unroll
  for (int kk = 0; kk < 4; ++kk) qf[kk] = *(const bf16x8*)(qptr + kk * 32);

  const f32x4 z4 = {0.f, 0.f, 0.f, 0.f};
  f32x4 oacc[8];
#pragma unroll
  for (int c = 0; c < 8; ++c) oacc[c] = z4;
  float m[4]    = {-1e30f, -1e30f, -1e30f, -1e30f};
  float lsum[4] = {0.f, 0.f, 0.f, 0.f};

  char* KtB = (char*)Kt;
  char* VtB = (char*)Vt;
  char* PlB = (char*)Pl + w * 2048;
  const float SCL2 = 0.08838834764831845f * 1.44269504088896f; // scale*log2e
  const int ntiles = 2 * qi + 2;
  const int wqmax = qrow0 + 15;

  for (int t = 0; t < ntiles; ++t) {
    const int kv0 = t * 64;
    __syncthreads();
#pragma unroll
    for (int it = 0; it < 2; ++it) {
      int cch = tid + it * 512;
      int r = cch >> 4, c = cch & 15;
      const bf16_t* src = qkv + (long)(kv0 + r) * QKVN + 4096 + kh * HDIM
                          + ((c ^ (r & 7)) * 8);
      gload_lds16(src, KtB + cch * 16);
    }
#pragma unroll
    for (int it = 0; it < 2; ++it) {
      int cch = tid + it * 512;
      int hd = cch >> 3, c = cch & 7;
      const bf16_t* src = vT + ((long)kh * HDIM + hd) * S_LEN + kv0
                          + ((c ^ (hd & 7)) * 8);
      gload_lds16(src, VtB + cch * 16);
    }
    __syncthreads();
    if (kv0 > wqmax) continue;

    f32x4 sf[4];
#pragma unroll
    for (int f = 0; f < 4; ++f) {
      f32x4 a = z4;
      int n = f * 16 + lr;
      int rb = n * 256, sw = (n & 7) << 4;
#pragma unroll
      for (int kk = 0; kk < 4; ++kk) {
        bf16x8 kf = *(const bf16x8*)(KtB + rb + (((kk * 4 + lg) * 16) ^ sw));
        a = __builtin_amdgcn_mfma_f32_16x16x32_bf16(qf[kk], kf, a, 0, 0, 0);
      }
      sf[f] = a;
    }

    // softmax (exp2 domain): mask only on diagonal tiles (wave-uniform).
    float sv[4][4], mx[4];
    if (kv0 + 63 <= qrow0) {          // fully unmasked for this wave
#pragma unroll
      for (int j = 0; j < 4; ++j) {
#pragma unroll
        for (int f = 0; f < 4; ++f) sv[j][f] = sf[f][j] * SCL2;
        float t0 = fmaxf(fmaxf(sv[j][0], sv[j][1]), fmaxf(sv[j][2], sv[j][3]));
        t0 = fmaxf(t0, __shfl_xor(t0, 1));
        t0 = fmaxf(t0, __shfl_xor(t0, 2));
        t0 = fmaxf(t0, __shfl_xor(t0, 4));
        t0 = fmaxf(t0, __shfl_xor(t0, 8));
        mx[j] = t0;
      }
    } else {
#pragma unroll
      for (int j = 0; j < 4; ++j) {
        int qrow = qrow0 + lg * 4 + j;
#pragma unroll
        for (int f = 0; f < 4; ++f) {
          float s = sf[f][j] * SCL2;
          if (kv0 + f * 16 + lr > qrow) s = -1e9f;
          sv[j][f] = s;
        }
        float t0 = fmaxf(fmaxf(sv[j][0], sv[j][1]), fmaxf(sv[j][2], sv[j][3]));
        t0 = fmaxf(t0, __shfl_xor(t0, 1));
        t0 = fmaxf(t0, __shfl_xor(t0, 2));
        t0 = fmaxf(t0, __shfl_xor(t0, 4));
        t0 = fmaxf(t0, __shfl_xor(t0, 8));
        mx[j] = t0;
      }
    }
    float g = fmaxf(fmaxf(mx[0] - m[0], mx[1] - m[1]),
                    fmaxf(mx[2] - m[2], mx[3] - m[3]));
    if (__any(g > 0.f)) {             // defer-max: rescale only when max grows
#pragma unroll
      for (int j = 0; j < 4; ++j) {
        float mn = fmaxf(m[j], mx[j]);
        float sc;
        asm("v_exp_f32 %0, %1" : "=v"(sc) : "v"(m[j] - mn));
        lsum[j] *= sc;
        m[j] = mn;
#pragma unroll
        for (int c = 0; c < 8; ++c) oacc[c][j] *= sc;
      }
    }
#pragma unroll
    for (int j = 0; j < 4; ++j) {
      float p[4];
#pragma unroll
      for (int f = 0; f < 4; ++f)
        asm("v_exp_f32 %0, %1" : "=v"(p[f]) : "v"(sv[j][f] - m[j]));
      float ps = (p[0] + p[1]) + (p[2] + p[3]);
      ps += __shfl_xor(ps, 1);
      ps += __shfl_xor(ps, 2);
      ps += __shfl_xor(ps, 4);
      ps += __shfl_xor(ps, 8);
      lsum[j] += ps;
      int row = lg * 4 + j;
      int swp = (row & 7) << 4;
#pragma unroll
      for (int f = 0; f < 4; ++f)
        *(unsigned short*)(PlB + row * 128 + (((f * 16 + lr) * 2) ^ swp)) = f2bf(p[f]);
    }

    bf16x8 pfr[2];
#pragma unroll
    for (int kk = 0; kk < 2; ++kk)
      pfr[kk] = *(const bf16x8*)(PlB + lr * 128 + (((kk * 4 + lg) * 16) ^ ((lr & 7) << 4)));
#pragma unroll
    for (int c = 0; c < 8; ++c) {
      int hd = c * 16 + lr;
      int rb = hd * 128, sw = (hd & 7) << 4;
#pragma unroll
      for (int kk = 0; kk < 2; ++kk) {
        bf16x8 vf = *(const bf16x8*)(VtB + rb + (((kk * 4 + lg) * 16) ^ sw));
        oacc[c] = __builtin_amdgcn_mfma_f32_16x16x32_bf16(pfr[kk], vf, oacc[c], 0, 0, 0);
      }
    }
  }

  float rl[4];
#pragma unroll
  for (int j = 0; j < 4; ++j) rl[j] = 1.f / lsum[j];
#pragma unroll
  for (int c = 0; c < 8; ++c)
#pragma unroll
    for (int j = 0; j < 4; ++j) {
      long row = qrow0 + lg * 4 + j;
      ob[row * 4096 + h * 128 + c * 16 + lr] = f2bf(oacc[c][j] * rl[j]);
    }
}

extern "C" void kernel_launch(void* const* d_in, const int* in_sizes, int n_in,
                              void* d_out, int out_size, void* d_ws, size_t ws_size,
                              hipStream_t stream) {
  const float* x  = (const float*)d_in[0];
  const float* wq = (const float*)d_in[1];
  const float* wk = (const float*)d_in[2];
  const float* wv = (const float*)d_in[3];
  const float* wo = (const float*)d_in[4];
  const float* fc = (const float*)d_in[5];
  const float* fs = (const float*)d_in[6];

  char* ws = (char*)d_ws;
  bf16_t* xb    = (bf16_t*)(ws + 0);          // 2048x4096 (dead after gemm1)
  bf16_t* wqkvb = (bf16_t*)(ws + 16777216);   // 6144x4096
  bf16_t* wob   = (bf16_t*)(ws + 67108864);   // 4096x4096
  bf16_t* qkv   = (bf16_t*)(ws + 100663296);  // 2048x6144
  bf16_t* ob    = (bf16_t*)(ws + 125829120);  // 2048x4096
  bf16_t* vT    = (bf16_t*)(ws + 0);          // 8x128x2048 (4 MB, reuses xb)

  cvt5_kernel<<<2048, 256, 0, stream>>>(x, wq, wk, wv, wo,
                                        (ushort4*)xb, (ushort4*)wqkvb, (ushort4*)wob);

  gemm8q<0><<<256, 512, 0, stream>>>(xb, wqkvb, qkv, 2048, 6144, 4096, 32);
  vtrans_kernel<<<dim3(8, 128), 256, 0, stream>>>(qkv, vT);
  rope_kernel<<<20480, 256, 0, stream>>>((unsigned int*)qkv, fc, fs);
  attn_kernel<<<dim3(32, 16), 512, 0, stream>>>(qkv, vT, (unsigned short*)ob);
  gemm2p<1><<<256, 512, 0, stream>>>(ob, wob, d_out, 2048, 4096, 4096, 32);
}

// Round 13
// 320.104 us; speedup vs baseline: 1.1237x; 1.0025x over previous
//
#include <hip/hip_runtime.h>
#include <hip/hip_bf16.h>
#include <stdint.h>

typedef __bf16 bf16_t;
typedef __attribute__((ext_vector_type(8))) __bf16 bf16x8;
typedef __attribute__((ext_vector_type(4))) float f32x4;
typedef __attribute__((ext_vector_type(8))) unsigned short u16x8;

#define S_LEN 2048
#define DIM   4096
#define QKVN  6144
#define NHEAD 32
#define HDIM  128

typedef __attribute__((address_space(1))) unsigned int as1_u32;
typedef __attribute__((address_space(3))) unsigned int as3_u32;

__device__ __forceinline__ unsigned short f2bf(float f) {
  unsigned u = __builtin_bit_cast(unsigned, f);
  u += 0x7fffu + ((u >> 16) & 1u);
  return (unsigned short)(u >> 16);
}

__device__ __forceinline__ void gload_lds16(const void* g, void* l) {
  __builtin_amdgcn_global_load_lds(
      (as1_u32*)(unsigned long long)(uintptr_t)g,
      (as3_u32*)(unsigned int)(uintptr_t)l,
      16, 0, 0);
}

// Fused f32->bf16 conversion for all 5 inputs (one launch, grid-stride).
__global__ __launch_bounds__(256) void cvt5_kernel(const float* __restrict__ x,
                                                   const float* __restrict__ wq,
                                                   const float* __restrict__ wk,
                                                   const float* __restrict__ wv,
                                                   const float* __restrict__ wo,
                                                   ushort4* __restrict__ xb,
                                                   ushort4* __restrict__ wqkvb,
                                                   ushort4* __restrict__ wob) {
  const long N0 = 2097152;           // x  : 2048*4096/4
  const long N1 = N0 + 4194304;      // wq : 4096*4096/4
  const long N2 = N1 + 1048576;      // wk
  const long N3 = N2 + 1048576;      // wv
  const long N4 = N3 + 4194304;      // wo
  long idx = (long)blockIdx.x * 256 + threadIdx.x;
  long stride = (long)gridDim.x * 256;
  for (long i = idx; i < N4; i += stride) {
    const float4* s; ushort4* d; long o;
    if (i < N0)      { s = (const float4*)x;  d = xb;              o = i; }
    else if (i < N1) { s = (const float4*)wq; d = wqkvb;           o = i - N0; }
    else if (i < N2) { s = (const float4*)wk; d = wqkvb + 4194304; o = i - N1; }
    else if (i < N3) { s = (const float4*)wv; d = wqkvb + 5242880; o = i - N2; }
    else             { s = (const float4*)wo; d = wob;             o = i - N3; }
    float4 v = s[o];
    ushort4 r;
    r.x = f2bf(v.x); r.y = f2bf(v.y); r.z = f2bf(v.z); r.w = f2bf(v.w);
    d[o] = r;
  }
}

// Shared swizzled LDS fragment read: chunk ^= (row&7), both sides.
__device__ __forceinline__ bf16x8 fld(const char* half, int row, int chunk) {
  return *(const bf16x8*)(half + row * 128 + ((chunk ^ (row & 7)) << 4));
}

// ---- 256x192 4-phase GEMM, BK=64, 8 waves (2M x 4N), A depth-2 staged ---
// A TRIPLE-buffered (3x32K), B double-buffered (2x24K) = 144KB LDS.
// Phases: P0 rd{A m0-1,B all}+stgA.h0(t+2); P1 rd{A m2-3}+stgA.h1(t+2);
// P2 rd{A m4-5}+stgB(t+2,t&1); P3 rd{A m6-7}+vmcnt(7).
// FIFO trace: end of tile t outstanding = [A(t+1):4,B(t+1):3]+[A(t+2):4,
// B(t+2):3]=14; vmcnt(7) drains A(t+1),B(t+1) exactly. Issue->wait distance
// for A = 7 phases (covers ~900cyc HBM; R11's depth-1 exposed ~400cyc).
template <int OUTF32>
__global__ __launch_bounds__(512, 2) void gemm8q(const bf16_t* __restrict__ A,
                                                 const bf16_t* __restrict__ B,
                                                 void* __restrict__ Cout,
                                                 int M, int N, int K, int nxt) {
  __shared__ char lds[147456];
  const int tid = threadIdx.x;
  const int lane = tid & 63, w = tid >> 6;
  const int wm = w >> 2, wn = w & 3;       // 2 M-waves x 4 N-waves
  const int lg = lane >> 4, lr = lane & 15;
  const int nwg = gridDim.x;
  const int orig = blockIdx.x;
  const int wgid = (orig & 7) * (nwg >> 3) + (orig >> 3);  // nwg % 8 == 0
  const int bx = wgid % nxt, by = wgid / nxt;
  const long rowA = (long)by * 256;
  const long rowB = (long)bx * 192;

  f32x4 acc[8][3];
  const f32x4 z4 = {0.f, 0.f, 0.f, 0.f};
#pragma unroll
  for (int i = 0; i < 8; ++i)
#pragma unroll
    for (int j = 0; j < 3; ++j) acc[i][j] = z4;

  const int r0 = tid >> 3, sl = tid & 7;
  const long xo  = (long)((sl ^ (r0 & 7)) << 3);
  const long aof = (rowA + r0) * (long)K + xo;
  const long bof = (rowB + r0) * (long)K + xo;
  const long j1  = (long)64 * K;
  const long h1  = (long)128 * K;
  const int ld0 = tid * 16, ld1 = (tid + 512) * 16, ld2 = (tid + 1024) * 16;

#define QSTG_A(K0, HALF, BUF3)                                                 \
  { char* hp = lds + (BUF3) * 32768 + (HALF) * 16384;                          \
    gload_lds16(A + aof + (HALF) * h1 + (K0),      hp + ld0);                  \
    gload_lds16(A + aof + (HALF) * h1 + j1 + (K0), hp + ld1); }
#define QSTG_B(K0, DBUF)                                                       \
  { char* bp = lds + 98304 + (DBUF) * 24576;                                   \
    gload_lds16(B + bof + (K0),          bp + ld0);                            \
    gload_lds16(B + bof + j1 + (K0),     bp + ld1);                            \
    gload_lds16(B + bof + 2 * j1 + (K0), bp + ld2); }

  const int nt = K >> 6;
  const int brow = wn * 48;

  // prologue: A(0),B(0),A(1),B(1) in FIFO order; vmcnt(7) -> tile0 landed.
  QSTG_A(0, 0, 0); QSTG_A(0, 1, 0); QSTG_B(0, 0);
  QSTG_A(64, 0, 1); QSTG_A(64, 1, 1); QSTG_B(64, 1);
  asm volatile("s_waitcnt vmcnt(7)" ::: "memory");
  __builtin_amdgcn_s_barrier();

  bf16x8 af[8][2], bf_[3][2];

  for (int t = 0; t < nt; ++t) {
    const int a3 = t % 3, s3 = (t + 2) % 3, d = t & 1;
    const char* Ah = lds + a3 * 32768 + wm * 16384;
    const char* Br = lds + 98304 + d * 24576;
    const int k2 = (t + 2) << 6;
    // ---- P0: read A m0-1 + B all; stage A.h0(t+2) ----
#pragma unroll
    for (int m = 0; m < 2; ++m) {
      af[m][0] = fld(Ah, m * 16 + lr, lg);
      af[m][1] = fld(Ah, m * 16 + lr, 4 + lg);
    }
#pragma unroll
    for (int n = 0; n < 3; ++n) {
      bf_[n][0] = fld(Br, brow + n * 16 + lr, lg);
      bf_[n][1] = fld(Br, brow + n * 16 + lr, 4 + lg);
    }
    if (t + 2 < nt) QSTG_A(k2, 0, s3);
    __builtin_amdgcn_s_barrier();
    asm volatile("s_waitcnt lgkmcnt(0)" ::: "memory");
    __builtin_amdgcn_sched_barrier(0);
    __builtin_amdgcn_s_setprio(1);
#pragma unroll
    for (int m = 0; m < 2; ++m)
#pragma unroll
      for (int n = 0; n < 3; ++n) {
        acc[m][n] = __builtin_amdgcn_mfma_f32_16x16x32_bf16(af[m][0], bf_[n][0], acc[m][n], 0, 0, 0);
        acc[m][n] = __builtin_amdgcn_mfma_f32_16x16x32_bf16(af[m][1], bf_[n][1], acc[m][n], 0, 0, 0);
      }
    __builtin_amdgcn_s_setprio(0);
    __builtin_amdgcn_s_barrier();
    // ---- P1: read A m2-3; stage A.h1(t+2) ----
#pragma unroll
    for (int m = 2; m < 4; ++m) {
      af[m][0] = fld(Ah, m * 16 + lr, lg);
      af[m][1] = fld(Ah, m * 16 + lr, 4 + lg);
    }
    if (t + 2 < nt) QSTG_A(k2, 1, s3);
    __builtin_amdgcn_s_barrier();
    asm volatile("s_waitcnt lgkmcnt(0)" ::: "memory");
    __builtin_amdgcn_sched_barrier(0);
    __builtin_amdgcn_s_setprio(1);
#pragma unroll
    for (int m = 2; m < 4; ++m)
#pragma unroll
      for (int n = 0; n < 3; ++n) {
        acc[m][n] = __builtin_amdgcn_mfma_f32_16x16x32_bf16(af[m][0], bf_[n][0], acc[m][n], 0, 0, 0);
        acc[m][n] = __builtin_amdgcn_mfma_f32_16x16x32_bf16(af[m][1], bf_[n][1], acc[m][n], 0, 0, 0);
      }
    __builtin_amdgcn_s_setprio(0);
    __builtin_amdgcn_s_barrier();
    // ---- P2: read A m4-5; stage B(t+2) into buf d (B(t) consumed @P0) ----
#pragma unroll
    for (int m = 4; m < 6; ++m) {
      af[m][0] = fld(Ah, m * 16 + lr, lg);
      af[m][1] = fld(Ah, m * 16 + lr, 4 + lg);
    }
    if (t + 2 < nt) QSTG_B(k2, d);
    __builtin_amdgcn_s_barrier();
    asm volatile("s_waitcnt lgkmcnt(0)" ::: "memory");
    __builtin_amdgcn_sched_barrier(0);
    __builtin_amdgcn_s_setprio(1);
#pragma unroll
    for (int m = 4; m < 6; ++m)
#pragma unroll
      for (int n = 0; n < 3; ++n) {
        acc[m][n] = __builtin_amdgcn_mfma_f32_16x16x32_bf16(af[m][0], bf_[n][0], acc[m][n], 0, 0, 0);
        acc[m][n] = __builtin_amdgcn_mfma_f32_16x16x32_bf16(af[m][1], bf_[n][1], acc[m][n], 0, 0, 0);
      }
    __builtin_amdgcn_s_setprio(0);
    __builtin_amdgcn_s_barrier();
    // ---- P3: read A m6-7; MFMA; vmcnt(7) ----
#pragma unroll
    for (int m = 6; m < 8; ++m) {
      af[m][0] = fld(Ah, m * 16 + lr, lg);
      af[m][1] = fld(Ah, m * 16 + lr, 4 + lg);
    }
    __builtin_amdgcn_s_barrier();
    asm volatile("s_waitcnt lgkmcnt(0)" ::: "memory");
    __builtin_amdgcn_sched_barrier(0);
    __builtin_amdgcn_s_setprio(1);
#pragma unroll
    for (int m = 6; m < 8; ++m)
#pragma unroll
      for (int n = 0; n < 3; ++n) {
        acc[m][n] = __builtin_amdgcn_mfma_f32_16x16x32_bf16(af[m][0], bf_[n][0], acc[m][n], 0, 0, 0);
        acc[m][n] = __builtin_amdgcn_mfma_f32_16x16x32_bf16(af[m][1], bf_[n][1], acc[m][n], 0, 0, 0);
      }
    __builtin_amdgcn_s_setprio(0);
    if (t + 2 < nt) {
      asm volatile("s_waitcnt vmcnt(7)" ::: "memory");
    } else {
      asm volatile("s_waitcnt vmcnt(0)" ::: "memory");
    }
    __builtin_amdgcn_s_barrier();
  }
#undef QSTG_A
#undef QSTG_B

  const long crow = rowA + wm * 128;
  const long ccol = rowB + wn * 48;
  unsigned short* C = (unsigned short*)Cout;
#pragma unroll
  for (int mf = 0; mf < 8; ++mf)
#pragma unroll
    for (int j = 0; j < 4; ++j) {
      long row = crow + mf * 16 + lg * 4 + j;
      unsigned short* cp = C + row * N + ccol + lr;
#pragma unroll
      for (int nf = 0; nf < 3; ++nf) cp[nf * 16] = f2bf(acc[mf][nf][j]);
    }
}

// ---- 256x128 2-phase GEMM, BK=64, 8 waves (R12-verified for O-proj) -----
template <int OUTF32>
__global__ __launch_bounds__(512, 2) void gemm2p(const bf16_t* __restrict__ A,
                                                 const bf16_t* __restrict__ B,
                                                 void* __restrict__ Cout,
                                                 int M, int N, int K, int nxt) {
  __shared__ char lds[147456];
  const int tid = threadIdx.x;
  const int lane = tid & 63, w = tid >> 6;
  const int wm = w >> 1, wn = w & 1;       // 4 M-waves x 2 N-waves, 64x64
  const int lg = lane >> 4, lr = lane & 15;
  const int nwg = gridDim.x;
  const int orig = blockIdx.x;
  const int wgid = (orig & 7) * (nwg >> 3) + (orig >> 3);  // nwg % 8 == 0
  const int bx = wgid % nxt, by = wgid / nxt;
  const long rowA = (long)by * 256;
  const long rowB = (long)bx * 128;

  f32x4 acc[4][4];
  const f32x4 z4 = {0.f, 0.f, 0.f, 0.f};
#pragma unroll
  for (int i = 0; i < 4; ++i)
#pragma unroll
    for (int j = 0; j < 4; ++j) acc[i][j] = z4;

  const int r0 = tid >> 3, sl = tid & 7;
  const long xo  = (long)((sl ^ (r0 & 7)) << 3);
  const long aof = (rowA + r0) * (long)K + xo;
  const long bof = (rowB + r0) * (long)K + xo;
  const long r64 = (long)64 * K;

#define PSTG_A(K0, BUF)                                                        \
  { char* ap = lds + (BUF) * 32768;                                            \
    gload_lds16(A + aof + (K0),           ap + tid * 16);                      \
    gload_lds16(A + aof + r64 + (K0),     ap + (tid + 512) * 16);              \
    gload_lds16(A + aof + 2 * r64 + (K0), ap + (tid + 1024) * 16);             \
    gload_lds16(A + aof + 3 * r64 + (K0), ap + (tid + 1536) * 16); }
#define PSTG_B(K0, BUF)                                                        \
  { char* bp = lds + 98304 + (BUF) * 16384;                                    \
    gload_lds16(B + bof + (K0),       bp + tid * 16);                          \
    gload_lds16(B + bof + r64 + (K0), bp + (tid + 512) * 16); }

  const int nt = K >> 6;

  PSTG_A(0, 0); PSTG_B(0, 0); PSTG_A(64, 1); PSTG_B(64, 1);
  asm volatile("s_waitcnt vmcnt(6)" ::: "memory");
  __builtin_amdgcn_s_barrier();

  bf16x8 af[4][2], bf_[4][2];

  for (int t = 0; t < nt; ++t) {
    const int b3 = t % 3, s3 = (t + 2) % 3;
    const char* Ab = lds + b3 * 32768;
    const char* Bb = lds + 98304 + b3 * 16384;
    const int arow = wm * 64, brow = wn * 64;
    const int k2 = (t + 2) << 6;
#pragma unroll
    for (int m = 0; m < 4; ++m) {
      af[m][0] = fld(Ab, arow + m * 16 + lr, lg);
      af[m][1] = fld(Ab, arow + m * 16 + lr, 4 + lg);
    }
#pragma unroll
    for (int n = 0; n < 2; ++n) {
      bf_[n][0] = fld(Bb, brow + n * 16 + lr, lg);
      bf_[n][1] = fld(Bb, brow + n * 16 + lr, 4 + lg);
    }
    if (t + 2 < nt) PSTG_A(k2, s3);
    __builtin_amdgcn_s_barrier();
    asm volatile("s_waitcnt lgkmcnt(0)" ::: "memory");
    __builtin_amdgcn_sched_barrier(0);
    __builtin_amdgcn_s_setprio(1);
#pragma unroll
    for (int m = 0; m < 4; ++m)
#pragma unroll
      for (int n = 0; n < 2; ++n) {
        acc[m][n] = __builtin_amdgcn_mfma_f32_16x16x32_bf16(af[m][0], bf_[n][0], acc[m][n], 0, 0, 0);
        acc[m][n] = __builtin_amdgcn_mfma_f32_16x16x32_bf16(af[m][1], bf_[n][1], acc[m][n], 0, 0, 0);
      }
    __builtin_amdgcn_s_setprio(0);
    __builtin_amdgcn_s_barrier();
#pragma unroll
    for (int n = 2; n < 4; ++n) {
      bf_[n][0] = fld(Bb, brow + n * 16 + lr, lg);
      bf_[n][1] = fld(Bb, brow + n * 16 + lr, 4 + lg);
    }
    if (t + 2 < nt) PSTG_B(k2, s3);
    __builtin_amdgcn_s_barrier();
    asm volatile("s_waitcnt lgkmcnt(0)" ::: "memory");
    __builtin_amdgcn_sched_barrier(0);
    __builtin_amdgcn_s_setprio(1);
#pragma unroll
    for (int m = 0; m < 4; ++m)
#pragma unroll
      for (int n = 2; n < 4; ++n) {
        acc[m][n] = __builtin_amdgcn_mfma_f32_16x16x32_bf16(af[m][0], bf_[n][0], acc[m][n], 0, 0, 0);
        acc[m][n] = __builtin_amdgcn_mfma_f32_16x16x32_bf16(af[m][1], bf_[n][1], acc[m][n], 0, 0, 0);
      }
    __builtin_amdgcn_s_setprio(0);
    if (t + 2 < nt) {
      asm volatile("s_waitcnt vmcnt(6)" ::: "memory");
    } else {
      asm volatile("s_waitcnt vmcnt(0)" ::: "memory");
    }
    __builtin_amdgcn_s_barrier();
  }
#undef PSTG_A
#undef PSTG_B

  const long crow = rowA + wm * 64;
  const long ccol = rowB + wn * 64;
  if (OUTF32) {
    float* C = (float*)Cout;
#pragma unroll
    for (int mf = 0; mf < 4; ++mf)
#pragma unroll
      for (int j = 0; j < 4; ++j) {
        long row = crow + mf * 16 + lg * 4 + j;
        float* cp = C + row * N + ccol + lr;
#pragma unroll
        for (int nf = 0; nf < 4; ++nf) cp[nf * 16] = acc[mf][nf][j];
      }
  } else {
    unsigned short* C = (unsigned short*)Cout;
#pragma unroll
    for (int mf = 0; mf < 4; ++mf)
#pragma unroll
      for (int j = 0; j < 4; ++j) {
        long row = crow + mf * 16 + lg * 4 + j;
        unsigned short* cp = C + row * N + ccol + lr;
#pragma unroll
        for (int nf = 0; nf < 4; ++nf) cp[nf * 16] = f2bf(acc[mf][nf][j]);
      }
  }
}

// In-place RoPE on bf16 qkv buffer (q heads 0..31, k heads 32..39).
__global__ __launch_bounds__(256) void rope_kernel(unsigned int* __restrict__ qkv32,
                                                   const float* __restrict__ cosb,
                                                   const float* __restrict__ sinb) {
  int t = blockIdx.x * 256 + threadIdx.x;
  int i  = t & 63;
  int sh = t >> 6;
  int hh = sh % 40;
  int s  = sh / 40;
  int col2 = (hh < 32) ? (hh * 64 + i) : (2048 + (hh - 32) * 64 + i);
  unsigned int* p = qkv32 + (long)s * (QKVN / 2) + col2;
  unsigned int v = *p;
  float tr = __builtin_bit_cast(float, (v & 0xffffu) << 16);
  float ti = __builtin_bit_cast(float, v & 0xffff0000u);
  float c  = cosb[s * 64 + i];
  float sn = sinb[s * 64 + i];
  float orr = tr * c - ti * sn;
  float oi  = tr * sn + ti * c;
  *p = (unsigned int)f2bf(orr) | ((unsigned int)f2bf(oi) << 16);
}

// V transpose: vT[kh][hd][s] from qkv[s][5120 + kh*128 + hd].
__global__ __launch_bounds__(256) void vtrans_kernel(const bf16_t* __restrict__ qkv,
                                                     bf16_t* __restrict__ vT) {
  const int kh = blockIdx.x;
  const int hd = threadIdx.x & 127;
  const int s0 = blockIdx.y * 16 + (threadIdx.x >> 7) * 8;
  u16x8 v;
#pragma unroll
  for (int e = 0; e < 8; ++e)
    v[e] = *(const unsigned short*)(qkv + (long)(s0 + e) * QKVN + 5120 + kh * HDIM + hd);
  *(u16x8*)(vT + ((long)kh * HDIM + hd) * S_LEN + s0) = v;
}

// Flash attention: 128 q-rows/block, 8 waves, KVBLK=64, K/V double-buffered.
// body(t) = { compute buf[t&1] (mask-skip wraps compute only) | barrier |
// stage K/V(t+2)->buf[t&1] | vmcnt(4) [t+1 landed, t+2 in flight] | barrier }
__global__ __launch_bounds__(512) void attn_kernel(const bf16_t* __restrict__ qkv,
                                                   const bf16_t* __restrict__ vT,
                                                   unsigned short* __restrict__ ob) {
  __shared__ bf16_t Kt[2][64 * 128];   // 2 x 16 KB
  __shared__ bf16_t Vt[2][128 * 64];   // 2 x 16 KB
  __shared__ bf16_t Pl[8 * 16 * 64];   // 16 KB
  const int h  = blockIdx.x;
  const int qi = 15 - (int)blockIdx.y;
  const int qb = qi * 128;
  const int kh = h >> 2;
  const int tid = threadIdx.x, lane = tid & 63, w = tid >> 6;
  const int lg = lane >> 4, lr = lane & 15;
  const int qrow0 = qb + w * 16;

  bf16x8 qf[4];
  const bf16_t* qptr = qkv + (long)(qrow0 + lr) * QKVN + h * HDIM + lg * 8;
#pragma unroll
  for (int kk = 0; kk < 4; ++kk) qf[kk] = *(const bf16x8*)(qptr + kk * 32);

  const f32x4 z4 = {0.f, 0.f, 0.f, 0.f};
  f32x4 oacc[8];
#pragma unroll
  for (int c = 0; c < 8; ++c) oacc[c] = z4;
  float m[4]    = {-1e30f, -1e30f, -1e30f, -1e30f};
  float lsum[4] = {0.f, 0.f, 0.f, 0.f};

  char* PlB = (char*)Pl + w * 2048;
  const float SCL2 = 0.08838834764831845f * 1.44269504088896f; // scale*log2e
  const int ntiles = 2 * qi + 2;                                // >= 2
  const int wqmax = qrow0 + 15;

#define STAGE_KV(T, BUF)                                                       \
  {                                                                            \
    const int kvs = (T) * 64;                                                  \
    _Pragma("unroll")                                                          \
    for (int it = 0; it < 2; ++it) {                                           \
      int cch = tid + it * 512;                                                \
      int r = cch >> 4, c = cch & 15;                                          \
      gload_lds16(qkv + (long)(kvs + r) * QKVN + 4096 + kh * HDIM              \
                      + ((c ^ (r & 7)) * 8),                                   \
                  (char*)Kt[BUF] + cch * 16);                                  \
    }                                                                          \
    _Pragma("unroll")                                                          \
    for (int it = 0; it < 2; ++it) {                                           \
      int cch = tid + it * 512;                                                \
      int hd2 = cch >> 3, c = cch & 7;                                         \
      gload_lds16(vT + ((long)kh * HDIM + hd2) * S_LEN + kvs                   \
                      + ((c ^ (hd2 & 7)) * 8),                                 \
                  (char*)Vt[BUF] + cch * 16);                                  \
    }                                                                          \
  }

  // prologue: tiles 0,1 staged; vmcnt(4) -> tile 0 landed.
  STAGE_KV(0, 0);
  STAGE_KV(1, 1);
  asm volatile("s_waitcnt vmcnt(4)" ::: "memory");
  __builtin_amdgcn_s_barrier();

  for (int t = 0; t < ntiles; ++t) {
    const int kv0 = t * 64;
    const int d = t & 1;
    if (kv0 <= wqmax) {
      char* KtB = (char*)Kt[d];
      char* VtB = (char*)Vt[d];

      f32x4 sf[4];
#pragma unroll
      for (int f = 0; f < 4; ++f) {
        f32x4 a = z4;
        int n = f * 16 + lr;
        int rb = n * 256, sw = (n & 7) << 4;
#pragma unroll
        for (int kk = 0; kk < 4; ++kk) {
          bf16x8 kf = *(const bf16x8*)(KtB + rb + (((kk * 4 + lg) * 16) ^ sw));
          a = __builtin_amdgcn_mfma_f32_16x16x32_bf16(qf[kk], kf, a, 0, 0, 0);
        }
        sf[f] = a;
      }

      float sv[4][4], mx[4];
      if (kv0 + 63 <= qrow0) {          // fully unmasked for this wave
#pragma unroll
        for (int j = 0; j < 4; ++j) {
#pragma unroll
          for (int f = 0; f < 4; ++f) sv[j][f] = sf[f][j] * SCL2;
          float t0 = fmaxf(fmaxf(sv[j][0], sv[j][1]), fmaxf(sv[j][2], sv[j][3]));
          t0 = fmaxf(t0, __shfl_xor(t0, 1));
          t0 = fmaxf(t0, __shfl_xor(t0, 2));
          t0 = fmaxf(t0, __shfl_xor(t0, 4));
          t0 = fmaxf(t0, __shfl_xor(t0, 8));
          mx[j] = t0;
        }
      } else {
#pragma unroll
        for (int j = 0; j < 4; ++j) {
          int qrow = qrow0 + lg * 4 + j;
#pragma unroll
          for (int f = 0; f < 4; ++f) {
            float s = sf[f][j] * SCL2;
            if (kv0 + f * 16 + lr > qrow) s = -1e9f;
            sv[j][f] = s;
          }
          float t0 = fmaxf(fmaxf(sv[j][0], sv[j][1]), fmaxf(sv[j][2], sv[j][3]));
          t0 = fmaxf(t0, __shfl_xor(t0, 1));
          t0 = fmaxf(t0, __shfl_xor(t0, 2));
          t0 = fmaxf(t0, __shfl_xor(t0, 4));
          t0 = fmaxf(t0, __shfl_xor(t0, 8));
          mx[j] = t0;
        }
      }
      float g = fmaxf(fmaxf(mx[0] - m[0], mx[1] - m[1]),
                      fmaxf(mx[2] - m[2], mx[3] - m[3]));
      if (__any(g > 0.f)) {             // defer-max rescale
#pragma unroll
        for (int j = 0; j < 4; ++j) {
          float mn = fmaxf(m[j], mx[j]);
          float sc;
          asm("v_exp_f32 %0, %1" : "=v"(sc) : "v"(m[j] - mn));
          lsum[j] *= sc;
          m[j] = mn;
#pragma unroll
          for (int c = 0; c < 8; ++c) oacc[c][j] *= sc;
        }
      }
#pragma unroll
      for (int j = 0; j < 4; ++j) {
        float p[4];
#pragma unroll
        for (int f = 0; f < 4; ++f)
          asm("v_exp_f32 %0, %1" : "=v"(p[f]) : "v"(sv[j][f] - m[j]));
        float ps = (p[0] + p[1]) + (p[2] + p[3]);
        ps += __shfl_xor(ps, 1);
        ps += __shfl_xor(ps, 2);
        ps += __shfl_xor(ps, 4);
        ps += __shfl_xor(ps, 8);
        lsum[j] += ps;
        int row = lg * 4 + j;
        int swp = (row & 7) << 4;
#pragma unroll
        for (int f = 0; f < 4; ++f)
          *(unsigned short*)(PlB + row * 128 + (((f * 16 + lr) * 2) ^ swp)) = f2bf(p[f]);
      }

      bf16x8 pfr[2];
#pragma unroll
      for (int kk = 0; kk < 2; ++kk)
        pfr[kk] = *(const bf16x8*)(PlB + lr * 128 + (((kk * 4 + lg) * 16) ^ ((lr & 7) << 4)));
#pragma unroll
      for (int c = 0; c < 8; ++c) {
        int hd = c * 16 + lr;
        int rb = hd * 128, sw = (hd & 7) << 4;
#pragma unroll
        for (int kk = 0; kk < 2; ++kk) {
          bf16x8 vf = *(const bf16x8*)(VtB + rb + (((kk * 4 + lg) * 16) ^ sw));
          oacc[c] = __builtin_amdgcn_mfma_f32_16x16x32_bf16(pfr[kk], vf, oacc[c], 0, 0, 0);
        }
      }
    }
    // ---- staging (all waves, regardless of mask-skip) ----
    __builtin_amdgcn_s_barrier();     // all waves done reading buf[d]
    if (t + 2 < ntiles) {
      STAGE_KV(t + 2, d);
      asm volatile("s_waitcnt vmcnt(4)" ::: "memory");  // tile t+1 landed
    } else {
      asm volatile("s_waitcnt vmcnt(0)" ::: "memory");
    }
    __builtin_amdgcn_s_barrier();
  }
#undef STAGE_KV

  float rl[4];
#pragma unroll
  for (int j = 0; j < 4; ++j) rl[j] = 1.f / lsum[j];
#pragma unroll
  for (int c = 0; c < 8; ++c)
#pragma unroll
    for (int j = 0; j < 4; ++j) {
      long row = qrow0 + lg * 4 + j;
      ob[row * 4096 + h * 128 + c * 16 + lr] = f2bf(oacc[c][j] * rl[j]);
    }
}

extern "C" void kernel_launch(void* const* d_in, const int* in_sizes, int n_in,
                              void* d_out, int out_size, void* d_ws, size_t ws_size,
                              hipStream_t stream) {
  const float* x  = (const float*)d_in[0];
  const float* wq = (const float*)d_in[1];
  const float* wk = (const float*)d_in[2];
  const float* wv = (const float*)d_in[3];
  const float* wo = (const float*)d_in[4];
  const float* fc = (const float*)d_in[5];
  const float* fs = (const float*)d_in[6];

  char* ws = (char*)d_ws;
  bf16_t* xb    = (bf16_t*)(ws + 0);          // 2048x4096 (dead after gemm1)
  bf16_t* wqkvb = (bf16_t*)(ws + 16777216);   // 6144x4096
  bf16_t* wob   = (bf16_t*)(ws + 67108864);   // 4096x4096
  bf16_t* qkv   = (bf16_t*)(ws + 100663296);  // 2048x6144
  bf16_t* ob    = (bf16_t*)(ws + 125829120);  // 2048x4096
  bf16_t* vT    = (bf16_t*)(ws + 0);          // 8x128x2048 (4 MB, reuses xb)

  cvt5_kernel<<<2048, 256, 0, stream>>>(x, wq, wk, wv, wo,
                                        (ushort4*)xb, (ushort4*)wqkvb, (ushort4*)wob);

  gemm8q<0><<<256, 512, 0, stream>>>(xb, wqkvb, qkv, 2048, 6144, 4096, 32);
  vtrans_kernel<<<dim3(8, 128), 256, 0, stream>>>(qkv, vT);
  rope_kernel<<<20480, 256, 0, stream>>>((unsigned int*)qkv, fc, fs);
  attn_kernel<<<dim3(32, 16), 512, 0, stream>>>(qkv, vT, (unsigned short*)ob);
  gemm2p<1><<<256, 512, 0, stream>>>(ob, wob, d_out, 2048, 4096, 4096, 32);
}

// Round 14
// 310.691 us; speedup vs baseline: 1.1577x; 1.0303x over previous
//
#include <hip/hip_runtime.h>
#include <hip/hip_bf16.h>
#include <stdint.h>

typedef __bf16 bf16_t;
typedef __attribute__((ext_vector_type(8))) __bf16 bf16x8;
typedef __attribute__((ext_vector_type(4))) float f32x4;
typedef __attribute__((ext_vector_type(8))) unsigned short u16x8;

#define S_LEN 2048
#define DIM   4096
#define QKVN  6144
#define NHEAD 32
#define HDIM  128

typedef __attribute__((address_space(1))) unsigned int as1_u32;
typedef __attribute__((address_space(3))) unsigned int as3_u32;

__device__ __forceinline__ unsigned short f2bf(float f) {
  unsigned u = __builtin_bit_cast(unsigned, f);
  u += 0x7fffu + ((u >> 16) & 1u);
  return (unsigned short)(u >> 16);
}

__device__ __forceinline__ void gload_lds16(const void* g, void* l) {
  __builtin_amdgcn_global_load_lds(
      (as1_u32*)(unsigned long long)(uintptr_t)g,
      (as3_u32*)(unsigned int)(uintptr_t)l,
      16, 0, 0);
}

// Fused f32->bf16 conversion for all 5 inputs (one launch, grid-stride).
__global__ __launch_bounds__(256) void cvt5_kernel(const float* __restrict__ x,
                                                   const float* __restrict__ wq,
                                                   const float* __restrict__ wk,
                                                   const float* __restrict__ wv,
                                                   const float* __restrict__ wo,
                                                   ushort4* __restrict__ xb,
                                                   ushort4* __restrict__ wqkvb,
                                                   ushort4* __restrict__ wob) {
  const long N0 = 2097152;           // x  : 2048*4096/4
  const long N1 = N0 + 4194304;      // wq : 4096*4096/4
  const long N2 = N1 + 1048576;      // wk
  const long N3 = N2 + 1048576;      // wv
  const long N4 = N3 + 4194304;      // wo
  long idx = (long)blockIdx.x * 256 + threadIdx.x;
  long stride = (long)gridDim.x * 256;
  for (long i = idx; i < N4; i += stride) {
    const float4* s; ushort4* d; long o;
    if (i < N0)      { s = (const float4*)x;  d = xb;              o = i; }
    else if (i < N1) { s = (const float4*)wq; d = wqkvb;           o = i - N0; }
    else if (i < N2) { s = (const float4*)wk; d = wqkvb + 4194304; o = i - N1; }
    else if (i < N3) { s = (const float4*)wv; d = wqkvb + 5242880; o = i - N2; }
    else             { s = (const float4*)wo; d = wob;             o = i - N3; }
    float4 v = s[o];
    ushort4 r;
    r.x = f2bf(v.x); r.y = f2bf(v.y); r.z = f2bf(v.z); r.w = f2bf(v.w);
    d[o] = r;
  }
}

// Shared swizzled LDS fragment read: chunk ^= (row&7), both sides.
__device__ __forceinline__ bf16x8 fld(const char* half, int row, int chunk) {
  return *(const bf16x8*)(half + row * 128 + ((chunk ^ (row & 7)) << 4));
}

// ---- 256x192 4-phase GEMM, BK=64, 8 waves (2M x 4N) (R11/R13: ~109us) ---
template <int OUTF32>
__global__ __launch_bounds__(512, 2) void gemm8q(const bf16_t* __restrict__ A,
                                                 const bf16_t* __restrict__ B,
                                                 void* __restrict__ Cout,
                                                 int M, int N, int K, int nxt) {
  __shared__ char lds[147456];
  const int tid = threadIdx.x;
  const int lane = tid & 63, w = tid >> 6;
  const int wm = w >> 2, wn = w & 3;       // 2 M-waves x 4 N-waves
  const int lg = lane >> 4, lr = lane & 15;
  const int nwg = gridDim.x;
  const int orig = blockIdx.x;
  const int wgid = (orig & 7) * (nwg >> 3) + (orig >> 3);  // nwg % 8 == 0
  const int bx = wgid % nxt, by = wgid / nxt;
  const long rowA = (long)by * 256;
  const long rowB = (long)bx * 192;

  f32x4 acc[8][3];
  const f32x4 z4 = {0.f, 0.f, 0.f, 0.f};
#pragma unroll
  for (int i = 0; i < 8; ++i)
#pragma unroll
    for (int j = 0; j < 3; ++j) acc[i][j] = z4;

  const int r0 = tid >> 3, sl = tid & 7;
  const long xo  = (long)((sl ^ (r0 & 7)) << 3);
  const long aof = (rowA + r0) * (long)K + xo;
  const long bof = (rowB + r0) * (long)K + xo;
  const long j1  = (long)64 * K;
  const long h1  = (long)128 * K;
  const int ld0 = tid * 16, ld1 = (tid + 512) * 16, ld2 = (tid + 1024) * 16;

#define QSTG_A(K0, HALF, BUF3)                                                 \
  { char* hp = lds + (BUF3) * 32768 + (HALF) * 16384;                          \
    gload_lds16(A + aof + (HALF) * h1 + (K0),      hp + ld0);                  \
    gload_lds16(A + aof + (HALF) * h1 + j1 + (K0), hp + ld1); }
#define QSTG_B(K0, DBUF)                                                       \
  { char* bp = lds + 98304 + (DBUF) * 24576;                                   \
    gload_lds16(B + bof + (K0),          bp + ld0);                            \
    gload_lds16(B + bof + j1 + (K0),     bp + ld1);                            \
    gload_lds16(B + bof + 2 * j1 + (K0), bp + ld2); }

  const int nt = K >> 6;
  const int brow = wn * 48;

  QSTG_A(0, 0, 0); QSTG_A(0, 1, 0); QSTG_B(0, 0);
  QSTG_A(64, 0, 1); QSTG_A(64, 1, 1); QSTG_B(64, 1);
  asm volatile("s_waitcnt vmcnt(7)" ::: "memory");
  __builtin_amdgcn_s_barrier();

  bf16x8 af[8][2], bf_[3][2];

  for (int t = 0; t < nt; ++t) {
    const int a3 = t % 3, s3 = (t + 2) % 3, d = t & 1;
    const char* Ah = lds + a3 * 32768 + wm * 16384;
    const char* Br = lds + 98304 + d * 24576;
    const int k2 = (t + 2) << 6;
#pragma unroll
    for (int m = 0; m < 2; ++m) {
      af[m][0] = fld(Ah, m * 16 + lr, lg);
      af[m][1] = fld(Ah, m * 16 + lr, 4 + lg);
    }
#pragma unroll
    for (int n = 0; n < 3; ++n) {
      bf_[n][0] = fld(Br, brow + n * 16 + lr, lg);
      bf_[n][1] = fld(Br, brow + n * 16 + lr, 4 + lg);
    }
    if (t + 2 < nt) QSTG_A(k2, 0, s3);
    __builtin_amdgcn_s_barrier();
    asm volatile("s_waitcnt lgkmcnt(0)" ::: "memory");
    __builtin_amdgcn_sched_barrier(0);
    __builtin_amdgcn_s_setprio(1);
#pragma unroll
    for (int m = 0; m < 2; ++m)
#pragma unroll
      for (int n = 0; n < 3; ++n) {
        acc[m][n] = __builtin_amdgcn_mfma_f32_16x16x32_bf16(af[m][0], bf_[n][0], acc[m][n], 0, 0, 0);
        acc[m][n] = __builtin_amdgcn_mfma_f32_16x16x32_bf16(af[m][1], bf_[n][1], acc[m][n], 0, 0, 0);
      }
    __builtin_amdgcn_s_setprio(0);
    __builtin_amdgcn_s_barrier();
#pragma unroll
    for (int m = 2; m < 4; ++m) {
      af[m][0] = fld(Ah, m * 16 + lr, lg);
      af[m][1] = fld(Ah, m * 16 + lr, 4 + lg);
    }
    if (t + 2 < nt) QSTG_A(k2, 1, s3);
    __builtin_amdgcn_s_barrier();
    asm volatile("s_waitcnt lgkmcnt(0)" ::: "memory");
    __builtin_amdgcn_sched_barrier(0);
    __builtin_amdgcn_s_setprio(1);
#pragma unroll
    for (int m = 2; m < 4; ++m)
#pragma unroll
      for (int n = 0; n < 3; ++n) {
        acc[m][n] = __builtin_amdgcn_mfma_f32_16x16x32_bf16(af[m][0], bf_[n][0], acc[m][n], 0, 0, 0);
        acc[m][n] = __builtin_amdgcn_mfma_f32_16x16x32_bf16(af[m][1], bf_[n][1], acc[m][n], 0, 0, 0);
      }
    __builtin_amdgcn_s_setprio(0);
    __builtin_amdgcn_s_barrier();
#pragma unroll
    for (int m = 4; m < 6; ++m) {
      af[m][0] = fld(Ah, m * 16 + lr, lg);
      af[m][1] = fld(Ah, m * 16 + lr, 4 + lg);
    }
    if (t + 2 < nt) QSTG_B(k2, d);
    __builtin_amdgcn_s_barrier();
    asm volatile("s_waitcnt lgkmcnt(0)" ::: "memory");
    __builtin_amdgcn_sched_barrier(0);
    __builtin_amdgcn_s_setprio(1);
#pragma unroll
    for (int m = 4; m < 6; ++m)
#pragma unroll
      for (int n = 0; n < 3; ++n) {
        acc[m][n] = __builtin_amdgcn_mfma_f32_16x16x32_bf16(af[m][0], bf_[n][0], acc[m][n], 0, 0, 0);
        acc[m][n] = __builtin_amdgcn_mfma_f32_16x16x32_bf16(af[m][1], bf_[n][1], acc[m][n], 0, 0, 0);
      }
    __builtin_amdgcn_s_setprio(0);
    __builtin_amdgcn_s_barrier();
#pragma unroll
    for (int m = 6; m < 8; ++m) {
      af[m][0] = fld(Ah, m * 16 + lr, lg);
      af[m][1] = fld(Ah, m * 16 + lr, 4 + lg);
    }
    __builtin_amdgcn_s_barrier();
    asm volatile("s_waitcnt lgkmcnt(0)" ::: "memory");
    __builtin_amdgcn_sched_barrier(0);
    __builtin_amdgcn_s_setprio(1);
#pragma unroll
    for (int m = 6; m < 8; ++m)
#pragma unroll
      for (int n = 0; n < 3; ++n) {
        acc[m][n] = __builtin_amdgcn_mfma_f32_16x16x32_bf16(af[m][0], bf_[n][0], acc[m][n], 0, 0, 0);
        acc[m][n] = __builtin_amdgcn_mfma_f32_16x16x32_bf16(af[m][1], bf_[n][1], acc[m][n], 0, 0, 0);
      }
    __builtin_amdgcn_s_setprio(0);
    if (t + 2 < nt) {
      asm volatile("s_waitcnt vmcnt(7)" ::: "memory");
    } else {
      asm volatile("s_waitcnt vmcnt(0)" ::: "memory");
    }
    __builtin_amdgcn_s_barrier();
  }
#undef QSTG_A
#undef QSTG_B

  const long crow = rowA + wm * 128;
  const long ccol = rowB + wn * 48;
  unsigned short* C = (unsigned short*)Cout;
#pragma unroll
  for (int mf = 0; mf < 8; ++mf)
#pragma unroll
    for (int j = 0; j < 4; ++j) {
      long row = crow + mf * 16 + lg * 4 + j;
      unsigned short* cp = C + row * N + ccol + lr;
#pragma unroll
      for (int nf = 0; nf < 3; ++nf) cp[nf * 16] = f2bf(acc[mf][nf][j]);
    }
}

// ---- 256x128 2-phase GEMM, BK=64, 8 waves (R12-verified for O-proj) -----
template <int OUTF32>
__global__ __launch_bounds__(512, 2) void gemm2p(const bf16_t* __restrict__ A,
                                                 const bf16_t* __restrict__ B,
                                                 void* __restrict__ Cout,
                                                 int M, int N, int K, int nxt) {
  __shared__ char lds[147456];
  const int tid = threadIdx.x;
  const int lane = tid & 63, w = tid >> 6;
  const int wm = w >> 1, wn = w & 1;       // 4 M-waves x 2 N-waves, 64x64
  const int lg = lane >> 4, lr = lane & 15;
  const int nwg = gridDim.x;
  const int orig = blockIdx.x;
  const int wgid = (orig & 7) * (nwg >> 3) + (orig >> 3);  // nwg % 8 == 0
  const int bx = wgid % nxt, by = wgid / nxt;
  const long rowA = (long)by * 256;
  const long rowB = (long)bx * 128;

  f32x4 acc[4][4];
  const f32x4 z4 = {0.f, 0.f, 0.f, 0.f};
#pragma unroll
  for (int i = 0; i < 4; ++i)
#pragma unroll
    for (int j = 0; j < 4; ++j) acc[i][j] = z4;

  const int r0 = tid >> 3, sl = tid & 7;
  const long xo  = (long)((sl ^ (r0 & 7)) << 3);
  const long aof = (rowA + r0) * (long)K + xo;
  const long bof = (rowB + r0) * (long)K + xo;
  const long r64 = (long)64 * K;

#define PSTG_A(K0, BUF)                                                        \
  { char* ap = lds + (BUF) * 32768;                                            \
    gload_lds16(A + aof + (K0),           ap + tid * 16);                      \
    gload_lds16(A + aof + r64 + (K0),     ap + (tid + 512) * 16);              \
    gload_lds16(A + aof + 2 * r64 + (K0), ap + (tid + 1024) * 16);             \
    gload_lds16(A + aof + 3 * r64 + (K0), ap + (tid + 1536) * 16); }
#define PSTG_B(K0, BUF)                                                        \
  { char* bp = lds + 98304 + (BUF) * 16384;                                    \
    gload_lds16(B + bof + (K0),       bp + tid * 16);                          \
    gload_lds16(B + bof + r64 + (K0), bp + (tid + 512) * 16); }

  const int nt = K >> 6;

  PSTG_A(0, 0); PSTG_B(0, 0); PSTG_A(64, 1); PSTG_B(64, 1);
  asm volatile("s_waitcnt vmcnt(6)" ::: "memory");
  __builtin_amdgcn_s_barrier();

  bf16x8 af[4][2], bf_[4][2];

  for (int t = 0; t < nt; ++t) {
    const int b3 = t % 3, s3 = (t + 2) % 3;
    const char* Ab = lds + b3 * 32768;
    const char* Bb = lds + 98304 + b3 * 16384;
    const int arow = wm * 64, brow = wn * 64;
    const int k2 = (t + 2) << 6;
#pragma unroll
    for (int m = 0; m < 4; ++m) {
      af[m][0] = fld(Ab, arow + m * 16 + lr, lg);
      af[m][1] = fld(Ab, arow + m * 16 + lr, 4 + lg);
    }
#pragma unroll
    for (int n = 0; n < 2; ++n) {
      bf_[n][0] = fld(Bb, brow + n * 16 + lr, lg);
      bf_[n][1] = fld(Bb, brow + n * 16 + lr, 4 + lg);
    }
    if (t + 2 < nt) PSTG_A(k2, s3);
    __builtin_amdgcn_s_barrier();
    asm volatile("s_waitcnt lgkmcnt(0)" ::: "memory");
    __builtin_amdgcn_sched_barrier(0);
    __builtin_amdgcn_s_setprio(1);
#pragma unroll
    for (int m = 0; m < 4; ++m)
#pragma unroll
      for (int n = 0; n < 2; ++n) {
        acc[m][n] = __builtin_amdgcn_mfma_f32_16x16x32_bf16(af[m][0], bf_[n][0], acc[m][n], 0, 0, 0);
        acc[m][n] = __builtin_amdgcn_mfma_f32_16x16x32_bf16(af[m][1], bf_[n][1], acc[m][n], 0, 0, 0);
      }
    __builtin_amdgcn_s_setprio(0);
    __builtin_amdgcn_s_barrier();
#pragma unroll
    for (int n = 2; n < 4; ++n) {
      bf_[n][0] = fld(Bb, brow + n * 16 + lr, lg);
      bf_[n][1] = fld(Bb, brow + n * 16 + lr, 4 + lg);
    }
    if (t + 2 < nt) PSTG_B(k2, s3);
    __builtin_amdgcn_s_barrier();
    asm volatile("s_waitcnt lgkmcnt(0)" ::: "memory");
    __builtin_amdgcn_sched_barrier(0);
    __builtin_amdgcn_s_setprio(1);
#pragma unroll
    for (int m = 0; m < 4; ++m)
#pragma unroll
      for (int n = 2; n < 4; ++n) {
        acc[m][n] = __builtin_amdgcn_mfma_f32_16x16x32_bf16(af[m][0], bf_[n][0], acc[m][n], 0, 0, 0);
        acc[m][n] = __builtin_amdgcn_mfma_f32_16x16x32_bf16(af[m][1], bf_[n][1], acc[m][n], 0, 0, 0);
      }
    __builtin_amdgcn_s_setprio(0);
    if (t + 2 < nt) {
      asm volatile("s_waitcnt vmcnt(6)" ::: "memory");
    } else {
      asm volatile("s_waitcnt vmcnt(0)" ::: "memory");
    }
    __builtin_amdgcn_s_barrier();
  }
#undef PSTG_A
#undef PSTG_B

  const long crow = rowA + wm * 64;
  const long ccol = rowB + wn * 64;
  if (OUTF32) {
    float* C = (float*)Cout;
#pragma unroll
    for (int mf = 0; mf < 4; ++mf)
#pragma unroll
      for (int j = 0; j < 4; ++j) {
        long row = crow + mf * 16 + lg * 4 + j;
        float* cp = C + row * N + ccol + lr;
#pragma unroll
        for (int nf = 0; nf < 4; ++nf) cp[nf * 16] = acc[mf][nf][j];
      }
  } else {
    unsigned short* C = (unsigned short*)Cout;
#pragma unroll
    for (int mf = 0; mf < 4; ++mf)
#pragma unroll
      for (int j = 0; j < 4; ++j) {
        long row = crow + mf * 16 + lg * 4 + j;
        unsigned short* cp = C + row * N + ccol + lr;
#pragma unroll
        for (int nf = 0; nf < 4; ++nf) cp[nf * 16] = f2bf(acc[mf][nf][j]);
      }
  }
}

// Merged prep: blocks [0,1024) = V transpose; blocks [1024, 21504) = RoPE.
// Disjoint qkv regions (V vs Q/K) -> no ordering hazard within the kernel.
__global__ __launch_bounds__(256) void prep_kernel(bf16_t* __restrict__ qkv,
                                                   bf16_t* __restrict__ vT,
                                                   const float* __restrict__ cosb,
                                                   const float* __restrict__ sinb) {
  const int bid = blockIdx.x;
  if (bid < 1024) {
    // V transpose: vT[kh][hd][s] from qkv[s][5120 + kh*128 + hd].
    const int kh = bid & 7;
    const int hd = threadIdx.x & 127;
    const int s0 = (bid >> 3) * 16 + (threadIdx.x >> 7) * 8;
    u16x8 v;
#pragma unroll
    for (int e = 0; e < 8; ++e)
      v[e] = *(const unsigned short*)(qkv + (long)(s0 + e) * QKVN + 5120 + kh * HDIM + hd);
    *(u16x8*)(vT + ((long)kh * HDIM + hd) * S_LEN + s0) = v;
  } else {
    // In-place RoPE (q heads 0..31, k heads 32..39).
    int t = (bid - 1024) * 256 + threadIdx.x;
    int i  = t & 63;
    int sh = t >> 6;
    int hh = sh % 40;
    int s  = sh / 40;
    int col2 = (hh < 32) ? (hh * 64 + i) : (2048 + (hh - 32) * 64 + i);
    unsigned int* p = (unsigned int*)qkv + (long)s * (QKVN / 2) + col2;
    unsigned int v = *p;
    float tr = __builtin_bit_cast(float, (v & 0xffffu) << 16);
    float ti = __builtin_bit_cast(float, v & 0xffff0000u);
    float c  = cosb[s * 64 + i];
    float sn = sinb[s * 64 + i];
    float orr = tr * c - ti * sn;
    float oi  = tr * sn + ti * c;
    *p = (unsigned int)f2bf(orr) | ((unsigned int)f2bf(oi) << 16);
  }
}

// Flash attention: 128 q-rows/block, 8 waves, KVBLK=64, K/V double-buffered.
// Softmax: NO per-tile butterflies — per-lane plsum (reduced once at end) +
// __any-gated max reduce (runs only when a lane's local max exceeds m).
__global__ __launch_bounds__(512) void attn_kernel(const bf16_t* __restrict__ qkv,
                                                   const bf16_t* __restrict__ vT,
                                                   unsigned short* __restrict__ ob) {
  __shared__ bf16_t Kt[2][64 * 128];   // 2 x 16 KB
  __shared__ bf16_t Vt[2][128 * 64];   // 2 x 16 KB
  __shared__ bf16_t Pl[8 * 16 * 64];   // 16 KB
  const int h  = blockIdx.x;
  const int qi = 15 - (int)blockIdx.y;
  const int qb = qi * 128;
  const int kh = h >> 2;
  const int tid = threadIdx.x, lane = tid & 63, w = tid >> 6;
  const int lg = lane >> 4, lr = lane & 15;
  const int qrow0 = qb + w * 16;

  bf16x8 qf[4];
  const bf16_t* qptr = qkv + (long)(qrow0 + lr) * QKVN + h * HDIM + lg * 8;
#pragma unroll
  for (int kk = 0; kk < 4; ++kk) qf[kk] = *(const bf16x8*)(qptr + kk * 32);

  const f32x4 z4 = {0.f, 0.f, 0.f, 0.f};
  f32x4 oacc[8];
#pragma unroll
  for (int c = 0; c < 8; ++c) oacc[c] = z4;
  float m[4]     = {-1e30f, -1e30f, -1e30f, -1e30f};
  float plsum[4] = {0.f, 0.f, 0.f, 0.f};

  char* PlB = (char*)Pl + w * 2048;
  const float SCL2 = 0.08838834764831845f * 1.44269504088896f; // scale*log2e
  const int ntiles = 2 * qi + 2;                                // >= 2
  const int wqmax = qrow0 + 15;

#define STAGE_KV(T, BUF)                                                       \
  {                                                                            \
    const int kvs = (T) * 64;                                                  \
    _Pragma("unroll")                                                          \
    for (int it = 0; it < 2; ++it) {                                           \
      int cch = tid + it * 512;                                                \
      int r = cch >> 4, c = cch & 15;                                          \
      gload_lds16(qkv + (long)(kvs + r) * QKVN + 4096 + kh * HDIM              \
                      + ((c ^ (r & 7)) * 8),                                   \
                  (char*)Kt[BUF] + cch * 16);                                  \
    }                                                                          \
    _Pragma("unroll")                                                          \
    for (int it = 0; it < 2; ++it) {                                           \
      int cch = tid + it * 512;                                                \
      int hd2 = cch >> 3, c = cch & 7;                                         \
      gload_lds16(vT + ((long)kh * HDIM + hd2) * S_LEN + kvs                   \
                      + ((c ^ (hd2 & 7)) * 8),                                 \
                  (char*)Vt[BUF] + cch * 16);                                  \
    }                                                                          \
  }

  STAGE_KV(0, 0);
  STAGE_KV(1, 1);
  asm volatile("s_waitcnt vmcnt(4)" ::: "memory");
  __builtin_amdgcn_s_barrier();

  for (int t = 0; t < ntiles; ++t) {
    const int kv0 = t * 64;
    const int d = t & 1;
    if (kv0 <= wqmax) {
      char* KtB = (char*)Kt[d];
      char* VtB = (char*)Vt[d];

      f32x4 sf[4];
#pragma unroll
      for (int f = 0; f < 4; ++f) {
        f32x4 a = z4;
        int n = f * 16 + lr;
        int rb = n * 256, sw = (n & 7) << 4;
#pragma unroll
        for (int kk = 0; kk < 4; ++kk) {
          bf16x8 kf = *(const bf16x8*)(KtB + rb + (((kk * 4 + lg) * 16) ^ sw));
          a = __builtin_amdgcn_mfma_f32_16x16x32_bf16(qf[kk], kf, a, 0, 0, 0);
        }
        sf[f] = a;
      }

      float sv[4][4], lmax[4];
      if (kv0 + 63 <= qrow0) {          // fully unmasked for this wave
#pragma unroll
        for (int j = 0; j < 4; ++j) {
#pragma unroll
          for (int f = 0; f < 4; ++f) sv[j][f] = sf[f][j] * SCL2;
          lmax[j] = fmaxf(fmaxf(sv[j][0], sv[j][1]), fmaxf(sv[j][2], sv[j][3]));
        }
      } else {
#pragma unroll
        for (int j = 0; j < 4; ++j) {
          int qrow = qrow0 + lg * 4 + j;
#pragma unroll
          for (int f = 0; f < 4; ++f) {
            float s = sf[f][j] * SCL2;
            if (kv0 + f * 16 + lr > qrow) s = -1e9f;
            sv[j][f] = s;
          }
          lmax[j] = fmaxf(fmaxf(sv[j][0], sv[j][1]), fmaxf(sv[j][2], sv[j][3]));
        }
      }
      // __any-gated max update: full butterfly + rescale only on growth.
      float g = fmaxf(fmaxf(lmax[0] - m[0], lmax[1] - m[1]),
                      fmaxf(lmax[2] - m[2], lmax[3] - m[3]));
      if (__any(g > 0.f)) {
#pragma unroll
        for (int j = 0; j < 4; ++j) {
          float t0 = lmax[j];
          t0 = fmaxf(t0, __shfl_xor(t0, 1));
          t0 = fmaxf(t0, __shfl_xor(t0, 2));
          t0 = fmaxf(t0, __shfl_xor(t0, 4));
          t0 = fmaxf(t0, __shfl_xor(t0, 8));
          float mn = fmaxf(m[j], t0);
          float sc;
          asm("v_exp_f32 %0, %1" : "=v"(sc) : "v"(m[j] - mn));
          plsum[j] *= sc;
          m[j] = mn;
#pragma unroll
          for (int c = 0; c < 8; ++c) oacc[c][j] *= sc;
        }
      }
#pragma unroll
      for (int j = 0; j < 4; ++j) {
        float p[4];
#pragma unroll
        for (int f = 0; f < 4; ++f)
          asm("v_exp_f32 %0, %1" : "=v"(p[f]) : "v"(sv[j][f] - m[j]));
        plsum[j] += (p[0] + p[1]) + (p[2] + p[3]);
        int row = lg * 4 + j;
        int swp = (row & 7) << 4;
#pragma unroll
        for (int f = 0; f < 4; ++f)
          *(unsigned short*)(PlB + row * 128 + (((f * 16 + lr) * 2) ^ swp)) = f2bf(p[f]);
      }

      bf16x8 pfr[2];
#pragma unroll
      for (int kk = 0; kk < 2; ++kk)
        pfr[kk] = *(const bf16x8*)(PlB + lr * 128 + (((kk * 4 + lg) * 16) ^ ((lr & 7) << 4)));
#pragma unroll
      for (int c = 0; c < 8; ++c) {
        int hd = c * 16 + lr;
        int rb = hd * 128, sw = (hd & 7) << 4;
#pragma unroll
        for (int kk = 0; kk < 2; ++kk) {
          bf16x8 vf = *(const bf16x8*)(VtB + rb + (((kk * 4 + lg) * 16) ^ sw));
          oacc[c] = __builtin_amdgcn_mfma_f32_16x16x32_bf16(pfr[kk], vf, oacc[c], 0, 0, 0);
        }
      }
    }
    __builtin_amdgcn_s_barrier();     // all waves done reading buf[d]
    if (t + 2 < ntiles) {
      STAGE_KV(t + 2, d);
      asm volatile("s_waitcnt vmcnt(4)" ::: "memory");  // tile t+1 landed
    } else {
      asm volatile("s_waitcnt vmcnt(0)" ::: "memory");
    }
    __builtin_amdgcn_s_barrier();
  }
#undef STAGE_KV

  float rl[4];
#pragma unroll
  for (int j = 0; j < 4; ++j) {
    float s = plsum[j];
    s += __shfl_xor(s, 1);
    s += __shfl_xor(s, 2);
    s += __shfl_xor(s, 4);
    s += __shfl_xor(s, 8);
    rl[j] = 1.f / s;
  }
#pragma unroll
  for (int c = 0; c < 8; ++c)
#pragma unroll
    for (int j = 0; j < 4; ++j) {
      long row = qrow0 + lg * 4 + j;
      ob[row * 4096 + h * 128 + c * 16 + lr] = f2bf(oacc[c][j] * rl[j]);
    }
}

extern "C" void kernel_launch(void* const* d_in, const int* in_sizes, int n_in,
                              void* d_out, int out_size, void* d_ws, size_t ws_size,
                              hipStream_t stream) {
  const float* x  = (const float*)d_in[0];
  const float* wq = (const float*)d_in[1];
  const float* wk = (const float*)d_in[2];
  const float* wv = (const float*)d_in[3];
  const float* wo = (const float*)d_in[4];
  const float* fc = (const float*)d_in[5];
  const float* fs = (const float*)d_in[6];

  char* ws = (char*)d_ws;
  bf16_t* xb    = (bf16_t*)(ws + 0);          // 2048x4096 (dead after gemm1)
  bf16_t* wqkvb = (bf16_t*)(ws + 16777216);   // 6144x4096
  bf16_t* wob   = (bf16_t*)(ws + 67108864);   // 4096x4096
  bf16_t* qkv   = (bf16_t*)(ws + 100663296);  // 2048x6144
  bf16_t* ob    = (bf16_t*)(ws + 125829120);  // 2048x4096
  bf16_t* vT    = (bf16_t*)(ws + 0);          // 8x128x2048 (4 MB, reuses xb)

  cvt5_kernel<<<2048, 256, 0, stream>>>(x, wq, wk, wv, wo,
                                        (ushort4*)xb, (ushort4*)wqkvb, (ushort4*)wob);

  gemm8q<0><<<256, 512, 0, stream>>>(xb, wqkvb, qkv, 2048, 6144, 4096, 32);
  prep_kernel<<<21504, 256, 0, stream>>>(qkv, vT, fc, fs);
  attn_kernel<<<dim3(32, 16), 512, 0, stream>>>(qkv, vT, (unsigned short*)ob);
  gemm2p<1><<<256, 512, 0, stream>>>(ob, wob, d_out, 2048, 4096, 4096, 32);
}